// Round 1
// baseline (9882.309 us; speedup 1.0000x reference)
//
#include <hip/hip_runtime.h>
#include <cmath>

// ---------------------------------------------------------------------------
// SeparateHiddenGCAEEncoder: 4 chained GCN convs with symmetric normalization.
//   P = D^-1/2 (A+I) D^-1/2
//   f2h = tanh(P (feature @ W_f2h) + b)
//   c2h = tanh(P (condition @ W_c2h) + b)
//   h   = [f2h | c2h]
//   h2  = tanh(P (h @ W_h2h) + b)
//   z   = P (h2 @ W_h2l) + b
// ---------------------------------------------------------------------------

// ---------------- degree / norm ----------------
__global__ void deg_init_kernel(float* __restrict__ deg, int N) {
    int i = blockIdx.x * 256 + threadIdx.x;
    if (i < N) deg[i] = 1.0f;  // self-loop contributes 1
}

__global__ void deg_count_kernel(const int* __restrict__ dst, float* __restrict__ deg, int E) {
    int e = blockIdx.x * 256 + threadIdx.x;
    if (e < E) atomicAdd(&deg[dst[e]], 1.0f);
}

__global__ void deg_finish_kernel(float* __restrict__ deg, int N) {
    int i = blockIdx.x * 256 + threadIdx.x;
    if (i < N) deg[i] = rsqrtf(deg[i]);  // deg >= 1 always
}

// ---------------- GEMM: out[N,M] = X[N,K] @ W[K,M] ----------------
// 64-row x M-col tile, BK=64 chunks. 256 threads = 16x16; each thread does a
// 4-row x (M/16)-col microtile. X staged transposed in LDS (pad 68 to avoid
// bank conflicts while keeping float4 alignment); W staged straight.
template <int K, int M>
__global__ __launch_bounds__(256) void gemm_kernel(const float* __restrict__ X,
                                                   const float* __restrict__ W,
                                                   float* __restrict__ out, int N) {
    constexpr int BM = 64, BK = 64;
    constexpr int CPT = M / 16;  // cols per thread: 8 (M=128) or 4 (M=64)
    constexpr int XP = 68;       // padded row stride for transposed x tile
    __shared__ float xs[BK * XP];
    __shared__ float ws[BK * M];

    const int tid = threadIdx.x;
    const int tx = tid & 15;
    const int ty = tid >> 4;
    const int row0 = blockIdx.x * BM;

    float acc[4][CPT];
#pragma unroll
    for (int r = 0; r < 4; ++r)
#pragma unroll
        for (int c = 0; c < CPT; ++c) acc[r][c] = 0.0f;

    for (int k0 = 0; k0 < K; k0 += BK) {
        // stage X tile (BM x BK), transposed into xs[k][row]
#pragma unroll
        for (int i = 0; i < (BM * BK) / (4 * 256); ++i) {  // 4 iters
            int flat4 = i * 256 + tid;
            int r = flat4 >> 4;          // row within tile (16 float4s per row)
            int kk = (flat4 & 15) * 4;   // k within tile
            float4 v = make_float4(0.f, 0.f, 0.f, 0.f);
            int row = row0 + r;
            if (row < N) v = *(const float4*)(X + (size_t)row * K + k0 + kk);
            xs[(kk + 0) * XP + r] = v.x;
            xs[(kk + 1) * XP + r] = v.y;
            xs[(kk + 2) * XP + r] = v.z;
            xs[(kk + 3) * XP + r] = v.w;
        }
        // stage W tile (BK x M), straight
#pragma unroll
        for (int i = 0; i < (BK * M) / (4 * 256); ++i) {  // 8 (M=128) or 4 (M=64)
            int flat4 = i * 256 + tid;
            int r = flat4 / (M / 4);
            int c = (flat4 % (M / 4)) * 4;
            *(float4*)(ws + r * M + c) = *(const float4*)(W + (size_t)(k0 + r) * M + c);
        }
        __syncthreads();

#pragma unroll 4
        for (int k = 0; k < BK; ++k) {
            float4 xv = *(const float4*)(xs + k * XP + ty * 4);
            float xr[4] = {xv.x, xv.y, xv.z, xv.w};
#pragma unroll
            for (int g = 0; g < CPT / 4; ++g) {
                float4 wv = *(const float4*)(ws + k * M + tx * CPT + g * 4);
                float wr[4] = {wv.x, wv.y, wv.z, wv.w};
#pragma unroll
                for (int r = 0; r < 4; ++r)
#pragma unroll
                    for (int c = 0; c < 4; ++c) acc[r][g * 4 + c] += xr[r] * wr[c];
            }
        }
        __syncthreads();
    }

    // writeback
#pragma unroll
    for (int r = 0; r < 4; ++r) {
        int row = row0 + ty * 4 + r;
        if (row < N) {
#pragma unroll
            for (int g = 0; g < CPT / 4; ++g) {
                float4 o = make_float4(acc[r][g * 4 + 0], acc[r][g * 4 + 1],
                                       acc[r][g * 4 + 2], acc[r][g * 4 + 3]);
                *(float4*)(out + (size_t)row * M + tx * CPT + g * 4) = o;
            }
        }
    }
}

// ---------------- output init: out[i, colOff+m] = b[m] + xl[i,m]*dinv[i]^2 ----------------
template <int M>
__global__ void init_out_kernel(const float* __restrict__ xl, const float* __restrict__ b,
                                const float* __restrict__ dinv, float* __restrict__ out,
                                int ld, int colOff, int N) {
    int idx = blockIdx.x * 256 + threadIdx.x;
    int i = idx / M;
    int m = idx & (M - 1);
    if (i < N) {
        float di = dinv[i];
        out[(size_t)i * ld + colOff + m] = b[m] + xl[(size_t)i * M + m] * di * di;
    }
}

// ---------------- edge scatter: out[dst] += xl[src] * dinv[src]*dinv[dst] ----------------
template <int M>
__global__ void scatter_kernel(const float* __restrict__ xl, const float* __restrict__ dinv,
                               const int* __restrict__ src, const int* __restrict__ dst,
                               float* __restrict__ out, int ld, int colOff, int E) {
    constexpr int TPE = M / 4;  // threads per edge (float4 each)
    int gid = blockIdx.x * 256 + threadIdx.x;
    int e = gid / TPE;
    int t = gid % TPE;
    if (e >= E) return;
    int s = src[e];
    int d = dst[e];
    float nrm = dinv[s] * dinv[d];
    float4 v = *(const float4*)(xl + (size_t)s * M + t * 4);
    float* o = out + (size_t)d * ld + colOff + t * 4;
    atomicAdd(o + 0, v.x * nrm);
    atomicAdd(o + 1, v.y * nrm);
    atomicAdd(o + 2, v.z * nrm);
    atomicAdd(o + 3, v.w * nrm);
}

// ---------------- elementwise tanh ----------------
__global__ void tanh_kernel(float* __restrict__ x, int n) {
    int i = blockIdx.x * 256 + threadIdx.x;
    if (i < n) x[i] = tanhf(x[i]);
}

// ---------------------------------------------------------------------------
extern "C" void kernel_launch(void* const* d_in, const int* in_sizes, int n_in,
                              void* d_out, int out_size, void* d_ws, size_t ws_size,
                              hipStream_t stream) {
    const int FD = 256, CD = 64, HD = 128, LD = 64;

    const float* feature   = (const float*)d_in[0];
    const float* condition = (const float*)d_in[1];
    const int*   edge      = (const int*)d_in[2];
    const float* W_f2h = (const float*)d_in[3];
    const float* b_f2h = (const float*)d_in[4];
    const float* W_c2h = (const float*)d_in[5];
    const float* b_c2h = (const float*)d_in[6];
    const float* W_h2h = (const float*)d_in[7];
    const float* b_h2h = (const float*)d_in[8];
    const float* W_h2l = (const float*)d_in[9];
    const float* b_h2l = (const float*)d_in[10];
    float* out = (float*)d_out;

    const int N = in_sizes[0] / FD;       // 100000
    const int E = in_sizes[2] / 2;        // 1600000
    const int* src = edge;
    const int* dst = edge + E;

    // workspace layout (floats)
    float* ws_f = (float*)d_ws;
    float* dinv = ws_f;                       // N
    float* A    = ws_f + (size_t)N;           // N*128 (xl scratch; conv4 uses N*64)
    float* B    = ws_f + (size_t)N * 129;     // N*256 (h = [f2h | c2h])
    float* C    = ws_f + (size_t)N * 385;     // N*128 (h2)

    const int TB = 256;
    dim3 blk(TB);

    // --- degrees -> dinv ---
    deg_init_kernel<<<(N + TB - 1) / TB, blk, 0, stream>>>(dinv, N);
    deg_count_kernel<<<(E + TB - 1) / TB, blk, 0, stream>>>(dst, dinv, E);
    deg_finish_kernel<<<(N + TB - 1) / TB, blk, 0, stream>>>(dinv, N);

    const int gemm_grid = (N + 63) / 64;

    // --- conv1: f2h (into B[:, 0:128]) ---
    gemm_kernel<256, 128><<<gemm_grid, blk, 0, stream>>>(feature, W_f2h, A, N);
    init_out_kernel<128><<<((size_t)N * HD + TB - 1) / TB, blk, 0, stream>>>(A, b_f2h, dinv, B, 256, 0, N);
    scatter_kernel<128><<<((size_t)E * 32 + TB - 1) / TB, blk, 0, stream>>>(A, dinv, src, dst, B, 256, 0, E);

    // --- conv2: c2h (into B[:, 128:256]) ---
    gemm_kernel<64, 128><<<gemm_grid, blk, 0, stream>>>(condition, W_c2h, A, N);
    init_out_kernel<128><<<((size_t)N * HD + TB - 1) / TB, blk, 0, stream>>>(A, b_c2h, dinv, B, 256, 128, N);
    scatter_kernel<128><<<((size_t)E * 32 + TB - 1) / TB, blk, 0, stream>>>(A, dinv, src, dst, B, 256, 128, E);

    // --- tanh(h) ---
    tanh_kernel<<<((size_t)N * 256 + TB - 1) / TB, blk, 0, stream>>>(B, N * 256);

    // --- conv3: h2 = tanh(P (h @ W_h2h) + b) ---
    gemm_kernel<256, 128><<<gemm_grid, blk, 0, stream>>>(B, W_h2h, A, N);
    init_out_kernel<128><<<((size_t)N * HD + TB - 1) / TB, blk, 0, stream>>>(A, b_h2h, dinv, C, 128, 0, N);
    scatter_kernel<128><<<((size_t)E * 32 + TB - 1) / TB, blk, 0, stream>>>(A, dinv, src, dst, C, 128, 0, E);
    tanh_kernel<<<((size_t)N * 128 + TB - 1) / TB, blk, 0, stream>>>(C, N * 128);

    // --- conv4: z = P (h2 @ W_h2l) + b ---
    gemm_kernel<128, 64><<<gemm_grid, blk, 0, stream>>>(C, W_h2l, A, N);
    init_out_kernel<64><<<((size_t)N * LD + TB - 1) / TB, blk, 0, stream>>>(A, b_h2l, dinv, out, 64, 0, N);
    scatter_kernel<64><<<((size_t)E * 16 + TB - 1) / TB, blk, 0, stream>>>(A, dinv, src, dst, out, 64, 0, E);
}

// Round 2
// 1312.357 us; speedup vs baseline: 7.5302x; 7.5302x over previous
//
#include <hip/hip_runtime.h>
#include <cmath>

// ---------------------------------------------------------------------------
// SeparateHiddenGCAEEncoder: 4 chained GCN convs, P = D^-1/2 (A+I) D^-1/2.
// Round 2: atomic scatter -> CSR (counting sort by dst) + register gather.
// Bias + self-loop + tanh fused into the gather kernel.
// ---------------------------------------------------------------------------

// ---------------- CSR build ----------------
__global__ void count_zero_kernel(int* __restrict__ count, int N) {
    int i = blockIdx.x * 256 + threadIdx.x;
    if (i < N) count[i] = 0;
}

__global__ void count_kernel(const int* __restrict__ dst, int* __restrict__ count, int E) {
    int e = blockIdx.x * 256 + threadIdx.x;
    if (e < E) atomicAdd(&count[dst[e]], 1);
}

__global__ void dinv_kernel(const int* __restrict__ count, float* __restrict__ dinv, int N) {
    int i = blockIdx.x * 256 + threadIdx.x;
    if (i < N) dinv[i] = rsqrtf((float)(count[i] + 1));  // +1 self loop
}

// single-block exclusive scan over count[0..N) -> row_ptr; also zeros cursor.
__global__ __launch_bounds__(1024) void scan_kernel(const int* __restrict__ count,
                                                    int* __restrict__ row_ptr,
                                                    int* __restrict__ cursor, int N) {
    __shared__ int sums[1024];
    const int t = threadIdx.x;
    const int C = (N + 1023) / 1024;
    int lo = t * C; if (lo > N) lo = N;
    int hi = lo + C; if (hi > N) hi = N;

    int s = 0;
    for (int i = lo; i < hi; ++i) s += count[i];
    sums[t] = s;
    __syncthreads();
    // Hillis-Steele inclusive scan
    for (int off = 1; off < 1024; off <<= 1) {
        int v = (t >= off) ? sums[t - off] : 0;
        __syncthreads();
        sums[t] += v;
        __syncthreads();
    }
    int run = (t == 0) ? 0 : sums[t - 1];
    for (int i = lo; i < hi; ++i) {
        row_ptr[i] = run;
        cursor[i] = 0;
        run += count[i];
    }
    if (t == 1023) row_ptr[N] = sums[1023];
}

// fill CSR entries: (src, norm) packed as int2
__global__ void fill_kernel(const int* __restrict__ src, const int* __restrict__ dst,
                            const float* __restrict__ dinv, const int* __restrict__ row_ptr,
                            int* __restrict__ cursor, int2* __restrict__ csr, int E) {
    int e = blockIdx.x * 256 + threadIdx.x;
    if (e >= E) return;
    int s = src[e];
    int d = dst[e];
    int pos = row_ptr[d] + atomicAdd(&cursor[d], 1);
    float nrm = dinv[s] * dinv[d];
    csr[pos] = make_int2(s, __float_as_int(nrm));
}

// ---------------- GEMM: out[N,M] = X[N,K] @ W[K,M] ----------------
template <int K, int M>
__global__ __launch_bounds__(256) void gemm_kernel(const float* __restrict__ X,
                                                   const float* __restrict__ W,
                                                   float* __restrict__ out, int N) {
    constexpr int BM = 64, BK = 64;
    constexpr int CPT = M / 16;
    constexpr int XP = 68;
    __shared__ float xs[BK * XP];
    __shared__ float ws[BK * M];

    const int tid = threadIdx.x;
    const int tx = tid & 15;
    const int ty = tid >> 4;
    const int row0 = blockIdx.x * BM;

    float acc[4][CPT];
#pragma unroll
    for (int r = 0; r < 4; ++r)
#pragma unroll
        for (int c = 0; c < CPT; ++c) acc[r][c] = 0.0f;

    for (int k0 = 0; k0 < K; k0 += BK) {
#pragma unroll
        for (int i = 0; i < (BM * BK) / (4 * 256); ++i) {
            int flat4 = i * 256 + tid;
            int r = flat4 >> 4;
            int kk = (flat4 & 15) * 4;
            float4 v = make_float4(0.f, 0.f, 0.f, 0.f);
            int row = row0 + r;
            if (row < N) v = *(const float4*)(X + (size_t)row * K + k0 + kk);
            xs[(kk + 0) * XP + r] = v.x;
            xs[(kk + 1) * XP + r] = v.y;
            xs[(kk + 2) * XP + r] = v.z;
            xs[(kk + 3) * XP + r] = v.w;
        }
#pragma unroll
        for (int i = 0; i < (BK * M) / (4 * 256); ++i) {
            int flat4 = i * 256 + tid;
            int r = flat4 / (M / 4);
            int c = (flat4 % (M / 4)) * 4;
            *(float4*)(ws + r * M + c) = *(const float4*)(W + (size_t)(k0 + r) * M + c);
        }
        __syncthreads();

#pragma unroll 4
        for (int k = 0; k < BK; ++k) {
            float4 xv = *(const float4*)(xs + k * XP + ty * 4);
            float xr[4] = {xv.x, xv.y, xv.z, xv.w};
#pragma unroll
            for (int g = 0; g < CPT / 4; ++g) {
                float4 wv = *(const float4*)(ws + k * M + tx * CPT + g * 4);
                float wr[4] = {wv.x, wv.y, wv.z, wv.w};
#pragma unroll
                for (int r = 0; r < 4; ++r)
#pragma unroll
                    for (int c = 0; c < 4; ++c) acc[r][g * 4 + c] += xr[r] * wr[c];
            }
        }
        __syncthreads();
    }

#pragma unroll
    for (int r = 0; r < 4; ++r) {
        int row = row0 + ty * 4 + r;
        if (row < N) {
#pragma unroll
            for (int g = 0; g < CPT / 4; ++g) {
                float4 o = make_float4(acc[r][g * 4 + 0], acc[r][g * 4 + 1],
                                       acc[r][g * 4 + 2], acc[r][g * 4 + 3]);
                *(float4*)(out + (size_t)row * M + tx * CPT + g * 4) = o;
            }
        }
    }
}

// ---------------- fused gather: out[i] = (tanh?)(b + xl[i]*dinv[i]^2 + sum_j xl[j]*nrm) ---
template <int M, bool TANH>
__global__ __launch_bounds__(256) void gather_kernel(const float* __restrict__ xl,
                                                     const float* __restrict__ b,
                                                     const float* __restrict__ dinv,
                                                     const int* __restrict__ row_ptr,
                                                     const int2* __restrict__ csr,
                                                     float* __restrict__ out,
                                                     int ld, int colOff, int N) {
    constexpr int TPN = M / 4;  // threads per node (float4 each): 32 or 16
    int gid = blockIdx.x * 256 + threadIdx.x;
    int node = gid / TPN;
    int t = gid % TPN;
    if (node >= N) return;

    float di = dinv[node];
    float4 bb = *(const float4*)(b + t * 4);
    float4 x = *(const float4*)(xl + (size_t)node * M + t * 4);
    float self = di * di;
    float4 acc;
    acc.x = bb.x + x.x * self;
    acc.y = bb.y + x.y * self;
    acc.z = bb.z + x.z * self;
    acc.w = bb.w + x.w * self;

    int p = row_ptr[node];
    const int p1 = row_ptr[node + 1];
    if (p < p1) {
        int2 en = csr[p];  // prefetch first descriptor
        for (;;) {
            int s = en.x;
            float nrm = __int_as_float(en.y);
            ++p;
            bool more = p < p1;
            if (more) en = csr[p];  // overlap next descriptor with row gather
            float4 v = *(const float4*)(xl + (size_t)s * M + t * 4);
            acc.x += v.x * nrm;
            acc.y += v.y * nrm;
            acc.z += v.z * nrm;
            acc.w += v.w * nrm;
            if (!more) break;
        }
    }

    if (TANH) {
        acc.x = tanhf(acc.x);
        acc.y = tanhf(acc.y);
        acc.z = tanhf(acc.z);
        acc.w = tanhf(acc.w);
    }
    *(float4*)(out + (size_t)node * ld + colOff + t * 4) = acc;
}

// ---------------------------------------------------------------------------
extern "C" void kernel_launch(void* const* d_in, const int* in_sizes, int n_in,
                              void* d_out, int out_size, void* d_ws, size_t ws_size,
                              hipStream_t stream) {
    const int FD = 256;

    const float* feature   = (const float*)d_in[0];
    const float* condition = (const float*)d_in[1];
    const int*   edge      = (const int*)d_in[2];
    const float* W_f2h = (const float*)d_in[3];
    const float* b_f2h = (const float*)d_in[4];
    const float* W_c2h = (const float*)d_in[5];
    const float* b_c2h = (const float*)d_in[6];
    const float* W_h2h = (const float*)d_in[7];
    const float* b_h2h = (const float*)d_in[8];
    const float* W_h2l = (const float*)d_in[9];
    const float* b_h2l = (const float*)d_in[10];
    float* out = (float*)d_out;

    const int N = in_sizes[0] / FD;   // 100000
    const int E = in_sizes[2] / 2;    // 1600000
    const int* src = edge;
    const int* dst = edge + E;

    // workspace layout
    float* ws_f   = (float*)d_ws;
    float* dinv   = ws_f;                                // N floats
    int*   count  = (int*)(ws_f + N);                    // N ints
    int*   rowp   = count + N;                           // N+1 ints
    int*   cursor = rowp + N + 1;                        // N ints
    // pad to 8B alignment for int2 (offset so far = 4N+1 words -> +1 pad)
    int2*  csr    = (int2*)(cursor + N + 1);             // E int2
    float* A      = (float*)(csr + E);                   // N*128 floats (xl scratch)
    float* B      = A + (size_t)N * 128;                 // N*256 floats (h; first half reused as h2)

    const int TB = 256;
    dim3 blk(TB);

    // --- CSR build + norms ---
    count_zero_kernel<<<(N + TB - 1) / TB, blk, 0, stream>>>(count, N);
    count_kernel<<<(E + TB - 1) / TB, blk, 0, stream>>>(dst, count, E);
    dinv_kernel<<<(N + TB - 1) / TB, blk, 0, stream>>>(count, dinv, N);
    scan_kernel<<<1, 1024, 0, stream>>>(count, rowp, cursor, N);
    fill_kernel<<<(E + TB - 1) / TB, blk, 0, stream>>>(src, dst, dinv, rowp, cursor, csr, E);

    const int gemm_grid = (N + 63) / 64;
    const int g128 = ((size_t)N * 32 + TB - 1) / TB;  // gather grid, M=128
    const int g64  = ((size_t)N * 16 + TB - 1) / TB;  // gather grid, M=64

    // --- conv1: f2h -> B[:, 0:128] ---
    gemm_kernel<256, 128><<<gemm_grid, blk, 0, stream>>>(feature, W_f2h, A, N);
    gather_kernel<128, true><<<g128, blk, 0, stream>>>(A, b_f2h, dinv, rowp, csr, B, 256, 0, N);

    // --- conv2: c2h -> B[:, 128:256] ---
    gemm_kernel<64, 128><<<gemm_grid, blk, 0, stream>>>(condition, W_c2h, A, N);
    gather_kernel<128, true><<<g128, blk, 0, stream>>>(A, b_c2h, dinv, rowp, csr, B, 256, 128, N);

    // --- conv3: h2 = tanh(P (h @ W_h2h) + b); h2 reuses B[0 : N*128] compact ---
    gemm_kernel<256, 128><<<gemm_grid, blk, 0, stream>>>(B, W_h2h, A, N);
    float* H2 = B;  // B fully consumed by gemm3; reuse as compact N x 128
    gather_kernel<128, true><<<g128, blk, 0, stream>>>(A, b_h2h, dinv, rowp, csr, H2, 128, 0, N);

    // --- conv4: z = P (h2 @ W_h2l) + b ---
    gemm_kernel<128, 64><<<gemm_grid, blk, 0, stream>>>(H2, W_h2l, A, N);
    gather_kernel<64, false><<<g64, blk, 0, stream>>>(A, b_h2l, dinv, rowp, csr, out, 64, 0, N);
}

// Round 3
// 1105.909 us; speedup vs baseline: 8.9359x; 1.1867x over previous
//
#include <hip/hip_runtime.h>
#include <cmath>

// ---------------------------------------------------------------------------
// SeparateHiddenGCAEEncoder: 4 chained GCN convs, P = D^-1/2 (A+I) D^-1/2.
// Round 3: single-block scan (230us) -> 3-pass multi-block scan (~15us).
// ---------------------------------------------------------------------------

// ---------------- CSR build ----------------
__global__ void count_zero_kernel(int* __restrict__ count, int N) {
    int i = blockIdx.x * 256 + threadIdx.x;
    if (i < N) count[i] = 0;
}

__global__ void count_kernel(const int* __restrict__ dst, int* __restrict__ count, int E) {
    int e = blockIdx.x * 256 + threadIdx.x;
    if (e < E) atomicAdd(&count[dst[e]], 1);
}

__global__ void dinv_kernel(const int* __restrict__ count, float* __restrict__ dinv, int N) {
    int i = blockIdx.x * 256 + threadIdx.x;
    if (i < N) dinv[i] = rsqrtf((float)(count[i] + 1));  // +1 self loop
}

// ---------------- 3-pass scan ----------------
constexpr int SCAN_VPT = 8;
constexpr int SCAN_TILE = 256 * SCAN_VPT;  // 2048

// pass 1: per-block sums
__global__ __launch_bounds__(256) void scan_partial_kernel(const int* __restrict__ count,
                                                           int* __restrict__ blocksums, int N) {
    __shared__ int red[256];
    const int t = threadIdx.x;
    int base = blockIdx.x * SCAN_TILE + t * SCAN_VPT;
    int s = 0;
#pragma unroll
    for (int i = 0; i < SCAN_VPT; ++i) {
        int idx = base + i;
        if (idx < N) s += count[idx];
    }
    red[t] = s;
    __syncthreads();
    for (int off = 128; off > 0; off >>= 1) {
        if (t < off) red[t] += red[t + off];
        __syncthreads();
    }
    if (t == 0) blocksums[blockIdx.x] = red[0];
}

// pass 2: exclusive scan of block sums (nb <= 1024), in place
__global__ __launch_bounds__(1024) void scan_blocksums_kernel(int* __restrict__ blocksums, int nb) {
    __shared__ int sh[1024];
    const int t = threadIdx.x;
    int v = (t < nb) ? blocksums[t] : 0;
    sh[t] = v;
    __syncthreads();
    for (int off = 1; off < 1024; off <<= 1) {
        int u = (t >= off) ? sh[t - off] : 0;
        __syncthreads();
        sh[t] += u;
        __syncthreads();
    }
    if (t < nb) blocksums[t] = sh[t] - v;  // exclusive
}

// pass 3: per-block exclusive scan + global offset -> row_ptr; zero cursor
__global__ __launch_bounds__(256) void scan_final_kernel(const int* __restrict__ count,
                                                         const int* __restrict__ blocksums,
                                                         int* __restrict__ row_ptr,
                                                         int* __restrict__ cursor, int N) {
    __shared__ int red[256];
    const int t = threadIdx.x;
    int base = blockIdx.x * SCAN_TILE + t * SCAN_VPT;
    int vals[SCAN_VPT];
    int s = 0;
#pragma unroll
    for (int i = 0; i < SCAN_VPT; ++i) {
        int idx = base + i;
        vals[i] = (idx < N) ? count[idx] : 0;
        s += vals[i];
    }
    red[t] = s;
    __syncthreads();
    for (int off = 1; off < 256; off <<= 1) {
        int u = (t >= off) ? red[t - off] : 0;
        __syncthreads();
        red[t] += u;
        __syncthreads();
    }
    int run = red[t] - s + blocksums[blockIdx.x];
#pragma unroll
    for (int i = 0; i < SCAN_VPT; ++i) {
        int idx = base + i;
        if (idx < N) {
            row_ptr[idx] = run;
            cursor[idx] = 0;
            run += vals[i];
            if (idx == N - 1) row_ptr[N] = run;
        }
    }
}

// fill CSR entries: (src, norm) packed as int2
__global__ void fill_kernel(const int* __restrict__ src, const int* __restrict__ dst,
                            const float* __restrict__ dinv, const int* __restrict__ row_ptr,
                            int* __restrict__ cursor, int2* __restrict__ csr, int E) {
    int e = blockIdx.x * 256 + threadIdx.x;
    if (e >= E) return;
    int s = src[e];
    int d = dst[e];
    int pos = row_ptr[d] + atomicAdd(&cursor[d], 1);
    float nrm = dinv[s] * dinv[d];
    csr[pos] = make_int2(s, __float_as_int(nrm));
}

// ---------------- GEMM: out[N,M] = X[N,K] @ W[K,M] ----------------
template <int K, int M>
__global__ __launch_bounds__(256) void gemm_kernel(const float* __restrict__ X,
                                                   const float* __restrict__ W,
                                                   float* __restrict__ out, int N) {
    constexpr int BM = 64, BK = 64;
    constexpr int CPT = M / 16;
    constexpr int XP = 68;
    __shared__ float xs[BK * XP];
    __shared__ float ws[BK * M];

    const int tid = threadIdx.x;
    const int tx = tid & 15;
    const int ty = tid >> 4;
    const int row0 = blockIdx.x * BM;

    float acc[4][CPT];
#pragma unroll
    for (int r = 0; r < 4; ++r)
#pragma unroll
        for (int c = 0; c < CPT; ++c) acc[r][c] = 0.0f;

    for (int k0 = 0; k0 < K; k0 += BK) {
#pragma unroll
        for (int i = 0; i < (BM * BK) / (4 * 256); ++i) {
            int flat4 = i * 256 + tid;
            int r = flat4 >> 4;
            int kk = (flat4 & 15) * 4;
            float4 v = make_float4(0.f, 0.f, 0.f, 0.f);
            int row = row0 + r;
            if (row < N) v = *(const float4*)(X + (size_t)row * K + k0 + kk);
            xs[(kk + 0) * XP + r] = v.x;
            xs[(kk + 1) * XP + r] = v.y;
            xs[(kk + 2) * XP + r] = v.z;
            xs[(kk + 3) * XP + r] = v.w;
        }
#pragma unroll
        for (int i = 0; i < (BK * M) / (4 * 256); ++i) {
            int flat4 = i * 256 + tid;
            int r = flat4 / (M / 4);
            int c = (flat4 % (M / 4)) * 4;
            *(float4*)(ws + r * M + c) = *(const float4*)(W + (size_t)(k0 + r) * M + c);
        }
        __syncthreads();

#pragma unroll 4
        for (int k = 0; k < BK; ++k) {
            float4 xv = *(const float4*)(xs + k * XP + ty * 4);
            float xr[4] = {xv.x, xv.y, xv.z, xv.w};
#pragma unroll
            for (int g = 0; g < CPT / 4; ++g) {
                float4 wv = *(const float4*)(ws + k * M + tx * CPT + g * 4);
                float wr[4] = {wv.x, wv.y, wv.z, wv.w};
#pragma unroll
                for (int r = 0; r < 4; ++r)
#pragma unroll
                    for (int c = 0; c < 4; ++c) acc[r][g * 4 + c] += xr[r] * wr[c];
            }
        }
        __syncthreads();
    }

#pragma unroll
    for (int r = 0; r < 4; ++r) {
        int row = row0 + ty * 4 + r;
        if (row < N) {
#pragma unroll
            for (int g = 0; g < CPT / 4; ++g) {
                float4 o = make_float4(acc[r][g * 4 + 0], acc[r][g * 4 + 1],
                                       acc[r][g * 4 + 2], acc[r][g * 4 + 3]);
                *(float4*)(out + (size_t)row * M + tx * CPT + g * 4) = o;
            }
        }
    }
}

// ---------------- fused gather: out[i] = (tanh?)(b + xl[i]*dinv[i]^2 + sum_j xl[j]*nrm) ---
template <int M, bool TANH>
__global__ __launch_bounds__(256) void gather_kernel(const float* __restrict__ xl,
                                                     const float* __restrict__ b,
                                                     const float* __restrict__ dinv,
                                                     const int* __restrict__ row_ptr,
                                                     const int2* __restrict__ csr,
                                                     float* __restrict__ out,
                                                     int ld, int colOff, int N) {
    constexpr int TPN = M / 4;  // threads per node (float4 each): 32 or 16
    int gid = blockIdx.x * 256 + threadIdx.x;
    int node = gid / TPN;
    int t = gid % TPN;
    if (node >= N) return;

    float di = dinv[node];
    float4 bb = *(const float4*)(b + t * 4);
    float4 x = *(const float4*)(xl + (size_t)node * M + t * 4);
    float self = di * di;
    float4 acc;
    acc.x = bb.x + x.x * self;
    acc.y = bb.y + x.y * self;
    acc.z = bb.z + x.z * self;
    acc.w = bb.w + x.w * self;

    int p = row_ptr[node];
    const int p1 = row_ptr[node + 1];
    if (p < p1) {
        int2 en = csr[p];  // prefetch first descriptor
        for (;;) {
            int s = en.x;
            float nrm = __int_as_float(en.y);
            ++p;
            bool more = p < p1;
            if (more) en = csr[p];  // overlap next descriptor with row gather
            float4 v = *(const float4*)(xl + (size_t)s * M + t * 4);
            acc.x += v.x * nrm;
            acc.y += v.y * nrm;
            acc.z += v.z * nrm;
            acc.w += v.w * nrm;
            if (!more) break;
        }
    }

    if (TANH) {
        acc.x = tanhf(acc.x);
        acc.y = tanhf(acc.y);
        acc.z = tanhf(acc.z);
        acc.w = tanhf(acc.w);
    }
    *(float4*)(out + (size_t)node * ld + colOff + t * 4) = acc;
}

// ---------------------------------------------------------------------------
extern "C" void kernel_launch(void* const* d_in, const int* in_sizes, int n_in,
                              void* d_out, int out_size, void* d_ws, size_t ws_size,
                              hipStream_t stream) {
    const int FD = 256;

    const float* feature   = (const float*)d_in[0];
    const float* condition = (const float*)d_in[1];
    const int*   edge      = (const int*)d_in[2];
    const float* W_f2h = (const float*)d_in[3];
    const float* b_f2h = (const float*)d_in[4];
    const float* W_c2h = (const float*)d_in[5];
    const float* b_c2h = (const float*)d_in[6];
    const float* W_h2h = (const float*)d_in[7];
    const float* b_h2h = (const float*)d_in[8];
    const float* W_h2l = (const float*)d_in[9];
    const float* b_h2l = (const float*)d_in[10];
    float* out = (float*)d_out;

    const int N = in_sizes[0] / FD;   // 100000
    const int E = in_sizes[2] / 2;    // 1600000
    const int* src = edge;
    const int* dst = edge + E;

    // workspace layout
    float* ws_f   = (float*)d_ws;
    float* dinv   = ws_f;                                // N floats
    int*   count  = (int*)(ws_f + N);                    // N ints
    int*   rowp   = count + N;                           // N+1 ints
    int*   cursor = rowp + N + 1;                        // N ints
    int*   bsums  = cursor + N;                          // 1024 ints
    int2*  csr    = (int2*)(((uintptr_t)(bsums + 1024) + 15) & ~(uintptr_t)15);  // E int2
    float* A      = (float*)(csr + E);                   // N*128 floats (xl scratch)
    float* B      = A + (size_t)N * 128;                 // N*256 floats (h; first half reused as h2)

    const int TB = 256;
    dim3 blk(TB);
    const int nScanBlocks = (N + SCAN_TILE - 1) / SCAN_TILE;  // 49

    // --- CSR build + norms ---
    count_zero_kernel<<<(N + TB - 1) / TB, blk, 0, stream>>>(count, N);
    count_kernel<<<(E + TB - 1) / TB, blk, 0, stream>>>(dst, count, E);
    dinv_kernel<<<(N + TB - 1) / TB, blk, 0, stream>>>(count, dinv, N);
    scan_partial_kernel<<<nScanBlocks, blk, 0, stream>>>(count, bsums, N);
    scan_blocksums_kernel<<<1, 1024, 0, stream>>>(bsums, nScanBlocks);
    scan_final_kernel<<<nScanBlocks, blk, 0, stream>>>(count, bsums, rowp, cursor, N);
    fill_kernel<<<(E + TB - 1) / TB, blk, 0, stream>>>(src, dst, dinv, rowp, cursor, csr, E);

    const int gemm_grid = (N + 63) / 64;
    const int g128 = ((size_t)N * 32 + TB - 1) / TB;  // gather grid, M=128
    const int g64  = ((size_t)N * 16 + TB - 1) / TB;  // gather grid, M=64

    // --- conv1: f2h -> B[:, 0:128] ---
    gemm_kernel<256, 128><<<gemm_grid, blk, 0, stream>>>(feature, W_f2h, A, N);
    gather_kernel<128, true><<<g128, blk, 0, stream>>>(A, b_f2h, dinv, rowp, csr, B, 256, 0, N);

    // --- conv2: c2h -> B[:, 128:256] ---
    gemm_kernel<64, 128><<<gemm_grid, blk, 0, stream>>>(condition, W_c2h, A, N);
    gather_kernel<128, true><<<g128, blk, 0, stream>>>(A, b_c2h, dinv, rowp, csr, B, 256, 128, N);

    // --- conv3: h2 = tanh(P (h @ W_h2h) + b); h2 reuses B compact ---
    gemm_kernel<256, 128><<<gemm_grid, blk, 0, stream>>>(B, W_h2h, A, N);
    float* H2 = B;  // B fully consumed by gemm3; reuse as compact N x 128
    gather_kernel<128, true><<<g128, blk, 0, stream>>>(A, b_h2h, dinv, rowp, csr, H2, 128, 0, N);

    // --- conv4: z = P (h2 @ W_h2l) + b ---
    gemm_kernel<128, 64><<<gemm_grid, blk, 0, stream>>>(H2, W_h2l, A, N);
    gather_kernel<64, false><<<g64, blk, 0, stream>>>(A, b_h2l, dinv, rowp, csr, out, 64, 0, N);
}

// Round 4
// 1029.408 us; speedup vs baseline: 9.6000x; 1.0743x over previous
//
#include <hip/hip_runtime.h>
#include <cmath>

// ---------------------------------------------------------------------------
// SeparateHiddenGCAEEncoder: 4 chained GCN convs, P = D^-1/2 (A+I) D^-1/2.
// Round 4: (a) conv2 reordered as (P·condition)@W (gather at 64-wide, bias+tanh
// fused into GEMM epilogue); (b) GEMM v2: BM=128, BK=32, 8-wide microtile rows,
// broadcast-friendly LDS reads.
// ---------------------------------------------------------------------------

// ---------------- CSR build ----------------
__global__ void count_zero_kernel(int* __restrict__ count, int N) {
    int i = blockIdx.x * 256 + threadIdx.x;
    if (i < N) count[i] = 0;
}

__global__ void count_kernel(const int* __restrict__ dst, int* __restrict__ count, int E) {
    int e = blockIdx.x * 256 + threadIdx.x;
    if (e < E) atomicAdd(&count[dst[e]], 1);
}

__global__ void dinv_kernel(const int* __restrict__ count, float* __restrict__ dinv, int N) {
    int i = blockIdx.x * 256 + threadIdx.x;
    if (i < N) dinv[i] = rsqrtf((float)(count[i] + 1));  // +1 self loop
}

// ---------------- 3-pass scan ----------------
constexpr int SCAN_VPT = 8;
constexpr int SCAN_TILE = 256 * SCAN_VPT;  // 2048

__global__ __launch_bounds__(256) void scan_partial_kernel(const int* __restrict__ count,
                                                           int* __restrict__ blocksums, int N) {
    __shared__ int red[256];
    const int t = threadIdx.x;
    int base = blockIdx.x * SCAN_TILE + t * SCAN_VPT;
    int s = 0;
#pragma unroll
    for (int i = 0; i < SCAN_VPT; ++i) {
        int idx = base + i;
        if (idx < N) s += count[idx];
    }
    red[t] = s;
    __syncthreads();
    for (int off = 128; off > 0; off >>= 1) {
        if (t < off) red[t] += red[t + off];
        __syncthreads();
    }
    if (t == 0) blocksums[blockIdx.x] = red[0];
}

__global__ __launch_bounds__(1024) void scan_blocksums_kernel(int* __restrict__ blocksums, int nb) {
    __shared__ int sh[1024];
    const int t = threadIdx.x;
    int v = (t < nb) ? blocksums[t] : 0;
    sh[t] = v;
    __syncthreads();
    for (int off = 1; off < 1024; off <<= 1) {
        int u = (t >= off) ? sh[t - off] : 0;
        __syncthreads();
        sh[t] += u;
        __syncthreads();
    }
    if (t < nb) blocksums[t] = sh[t] - v;  // exclusive
}

__global__ __launch_bounds__(256) void scan_final_kernel(const int* __restrict__ count,
                                                         const int* __restrict__ blocksums,
                                                         int* __restrict__ row_ptr,
                                                         int* __restrict__ cursor, int N) {
    __shared__ int red[256];
    const int t = threadIdx.x;
    int base = blockIdx.x * SCAN_TILE + t * SCAN_VPT;
    int vals[SCAN_VPT];
    int s = 0;
#pragma unroll
    for (int i = 0; i < SCAN_VPT; ++i) {
        int idx = base + i;
        vals[i] = (idx < N) ? count[idx] : 0;
        s += vals[i];
    }
    red[t] = s;
    __syncthreads();
    for (int off = 1; off < 256; off <<= 1) {
        int u = (t >= off) ? red[t - off] : 0;
        __syncthreads();
        red[t] += u;
        __syncthreads();
    }
    int run = red[t] - s + blocksums[blockIdx.x];
#pragma unroll
    for (int i = 0; i < SCAN_VPT; ++i) {
        int idx = base + i;
        if (idx < N) {
            row_ptr[idx] = run;
            cursor[idx] = 0;
            run += vals[i];
            if (idx == N - 1) row_ptr[N] = run;
        }
    }
}

__global__ void fill_kernel(const int* __restrict__ src, const int* __restrict__ dst,
                            const float* __restrict__ dinv, const int* __restrict__ row_ptr,
                            int* __restrict__ cursor, int2* __restrict__ csr, int E) {
    int e = blockIdx.x * 256 + threadIdx.x;
    if (e >= E) return;
    int s = src[e];
    int d = dst[e];
    int pos = row_ptr[d] + atomicAdd(&cursor[d], 1);
    float nrm = dinv[s] * dinv[d];
    csr[pos] = make_int2(s, __float_as_int(nrm));
}

// ---------------- GEMM v2: out[N,M](ld,colOff) = X[N,K] @ W[K,M] (+bias,tanh) --
// 256 threads = 16x16. BM=128 rows/block, BK=32. Each thread: 8 rows x (M/16)
// cols. X staged transposed (xs[k][row], pad 132); W staged straight. Inner
// LDS reads broadcast across lanes (X addr depends on ty only, W on tx only).
template <int K, int M, bool BIAS_TANH>
__global__ __launch_bounds__(256) void gemm_kernel(const float* __restrict__ X,
                                                   const float* __restrict__ W,
                                                   const float* __restrict__ bias,
                                                   float* __restrict__ out,
                                                   int ld, int colOff, int N) {
    constexpr int BM = 128, BK = 32;
    constexpr int CN = M / 16;   // cols per thread: 8 (M=128) or 4 (M=64)
    constexpr int XP = 132;      // padded row stride (multiple of 4 for b128)
    __shared__ float xs[BK * XP];
    __shared__ float ws[BK * M];

    const int tid = threadIdx.x;
    const int tx = tid & 15;
    const int ty = tid >> 4;
    const int row0 = blockIdx.x * BM;

    float acc[8][CN];
#pragma unroll
    for (int r = 0; r < 8; ++r)
#pragma unroll
        for (int c = 0; c < CN; ++c) acc[r][c] = 0.0f;

    for (int k0 = 0; k0 < K; k0 += BK) {
        // stage X tile (BM x BK) transposed: 1024 float4 loads / 256 threads
#pragma unroll
        for (int i = 0; i < 4; ++i) {
            int flat4 = i * 256 + tid;
            int r = flat4 >> 3;          // row in tile
            int k = (flat4 & 7) * 4;     // k in tile
            float4 v = make_float4(0.f, 0.f, 0.f, 0.f);
            int row = row0 + r;
            if (row < N) v = *(const float4*)(X + (size_t)row * K + k0 + k);
            xs[(k + 0) * XP + r] = v.x;
            xs[(k + 1) * XP + r] = v.y;
            xs[(k + 2) * XP + r] = v.z;
            xs[(k + 3) * XP + r] = v.w;
        }
        // stage W tile (BK x M)
#pragma unroll
        for (int i = 0; i < (BK * M) / (4 * 256); ++i) {  // 4 (M=128) or 2 (M=64)
            int flat4 = i * 256 + tid;
            int r = flat4 / (M / 4);
            int c = (flat4 % (M / 4)) * 4;
            *(float4*)(ws + r * M + c) = *(const float4*)(W + (size_t)(k0 + r) * M + c);
        }
        __syncthreads();

#pragma unroll 4
        for (int k = 0; k < BK; ++k) {
            const float* xp = xs + k * XP + ty * 8;
            float4 xa = *(const float4*)(xp);
            float4 xb = *(const float4*)(xp + 4);
            float xr[8] = {xa.x, xa.y, xa.z, xa.w, xb.x, xb.y, xb.z, xb.w};
            const float* wp = ws + k * M + tx * CN;
            float wr[CN];
#pragma unroll
            for (int g = 0; g < CN / 4; ++g) {
                float4 wv = *(const float4*)(wp + g * 4);
                wr[g * 4 + 0] = wv.x;
                wr[g * 4 + 1] = wv.y;
                wr[g * 4 + 2] = wv.z;
                wr[g * 4 + 3] = wv.w;
            }
#pragma unroll
            for (int r = 0; r < 8; ++r)
#pragma unroll
                for (int c = 0; c < CN; ++c) acc[r][c] += xr[r] * wr[c];
        }
        __syncthreads();
    }

    float brs[CN];
    if (BIAS_TANH) {
#pragma unroll
        for (int c = 0; c < CN; ++c) brs[c] = bias[tx * CN + c];
    }

#pragma unroll
    for (int r = 0; r < 8; ++r) {
        int row = row0 + ty * 8 + r;
        if (row < N) {
            float* op = out + (size_t)row * ld + colOff + tx * CN;
#pragma unroll
            for (int g = 0; g < CN / 4; ++g) {
                float4 o;
                if (BIAS_TANH) {
                    o.x = tanhf(acc[r][g * 4 + 0] + brs[g * 4 + 0]);
                    o.y = tanhf(acc[r][g * 4 + 1] + brs[g * 4 + 1]);
                    o.z = tanhf(acc[r][g * 4 + 2] + brs[g * 4 + 2]);
                    o.w = tanhf(acc[r][g * 4 + 3] + brs[g * 4 + 3]);
                } else {
                    o = make_float4(acc[r][g * 4 + 0], acc[r][g * 4 + 1],
                                    acc[r][g * 4 + 2], acc[r][g * 4 + 3]);
                }
                *(float4*)(op + g * 4) = o;
            }
        }
    }
}

// ---------------- fused gather: out[i] = (tanh?)((b?) + xl[i]*dinv[i]^2 + sum_j xl[j]*nrm)
template <int M, bool TANH, bool HAS_BIAS>
__global__ __launch_bounds__(256) void gather_kernel(const float* __restrict__ xl,
                                                     const float* __restrict__ b,
                                                     const float* __restrict__ dinv,
                                                     const int* __restrict__ row_ptr,
                                                     const int2* __restrict__ csr,
                                                     float* __restrict__ out,
                                                     int ld, int colOff, int N) {
    constexpr int TPN = M / 4;  // threads per node (float4 each): 32 or 16
    int gid = blockIdx.x * 256 + threadIdx.x;
    int node = gid / TPN;
    int t = gid % TPN;
    if (node >= N) return;

    float di = dinv[node];
    float4 x = *(const float4*)(xl + (size_t)node * M + t * 4);
    float self = di * di;
    float4 acc;
    acc.x = x.x * self;
    acc.y = x.y * self;
    acc.z = x.z * self;
    acc.w = x.w * self;
    if (HAS_BIAS) {
        float4 bb = *(const float4*)(b + t * 4);
        acc.x += bb.x;
        acc.y += bb.y;
        acc.z += bb.z;
        acc.w += bb.w;
    }

    int p = row_ptr[node];
    const int p1 = row_ptr[node + 1];
    if (p < p1) {
        int2 en = csr[p];  // prefetch first descriptor
        for (;;) {
            int s = en.x;
            float nrm = __int_as_float(en.y);
            ++p;
            bool more = p < p1;
            if (more) en = csr[p];  // overlap next descriptor with row gather
            float4 v = *(const float4*)(xl + (size_t)s * M + t * 4);
            acc.x += v.x * nrm;
            acc.y += v.y * nrm;
            acc.z += v.z * nrm;
            acc.w += v.w * nrm;
            if (!more) break;
        }
    }

    if (TANH) {
        acc.x = tanhf(acc.x);
        acc.y = tanhf(acc.y);
        acc.z = tanhf(acc.z);
        acc.w = tanhf(acc.w);
    }
    *(float4*)(out + (size_t)node * ld + colOff + t * 4) = acc;
}

// ---------------------------------------------------------------------------
extern "C" void kernel_launch(void* const* d_in, const int* in_sizes, int n_in,
                              void* d_out, int out_size, void* d_ws, size_t ws_size,
                              hipStream_t stream) {
    const int FD = 256;

    const float* feature   = (const float*)d_in[0];
    const float* condition = (const float*)d_in[1];
    const int*   edge      = (const int*)d_in[2];
    const float* W_f2h = (const float*)d_in[3];
    const float* b_f2h = (const float*)d_in[4];
    const float* W_c2h = (const float*)d_in[5];
    const float* b_c2h = (const float*)d_in[6];
    const float* W_h2h = (const float*)d_in[7];
    const float* b_h2h = (const float*)d_in[8];
    const float* W_h2l = (const float*)d_in[9];
    const float* b_h2l = (const float*)d_in[10];
    float* out = (float*)d_out;

    const int N = in_sizes[0] / FD;   // 100000
    const int E = in_sizes[2] / 2;    // 1600000
    const int* src = edge;
    const int* dst = edge + E;

    // workspace layout
    float* ws_f   = (float*)d_ws;
    float* dinv   = ws_f;                                // N floats
    int*   count  = (int*)(ws_f + N);                    // N ints
    int*   rowp   = count + N;                           // N+1 ints
    int*   cursor = rowp + N + 1;                        // N ints
    int*   bsums  = cursor + N;                          // 1024 ints
    int2*  csr    = (int2*)(((uintptr_t)(bsums + 1024) + 15) & ~(uintptr_t)15);  // E int2
    float* A      = (float*)(csr + E);                   // N*128 floats (scratch)
    float* B      = A + (size_t)N * 128;                 // N*256 floats (h; reused as h2)

    const int TB = 256;
    dim3 blk(TB);
    const int nScanBlocks = (N + SCAN_TILE - 1) / SCAN_TILE;  // 49

    // --- CSR build + norms ---
    count_zero_kernel<<<(N + TB - 1) / TB, blk, 0, stream>>>(count, N);
    count_kernel<<<(E + TB - 1) / TB, blk, 0, stream>>>(dst, count, E);
    dinv_kernel<<<(N + TB - 1) / TB, blk, 0, stream>>>(count, dinv, N);
    scan_partial_kernel<<<nScanBlocks, blk, 0, stream>>>(count, bsums, N);
    scan_blocksums_kernel<<<1, 1024, 0, stream>>>(bsums, nScanBlocks);
    scan_final_kernel<<<nScanBlocks, blk, 0, stream>>>(count, bsums, rowp, cursor, N);
    fill_kernel<<<(E + TB - 1) / TB, blk, 0, stream>>>(src, dst, dinv, rowp, cursor, csr, E);

    const int gemm_grid = (N + 127) / 128;
    const int g128 = ((size_t)N * 32 + TB - 1) / TB;  // gather grid, M=128
    const int g64  = ((size_t)N * 16 + TB - 1) / TB;  // gather grid, M=64

    // --- conv1: f2h = tanh(P(feature@W)+b) -> B[:, 0:128] ---
    gemm_kernel<256, 128, false><<<gemm_grid, blk, 0, stream>>>(feature, W_f2h, nullptr, A, 128, 0, N);
    gather_kernel<128, true, true><<<g128, blk, 0, stream>>>(A, b_f2h, dinv, rowp, csr, B, 256, 0, N);

    // --- conv2 (reordered): cprop = P·condition (64-wide), then tanh(cprop@W+b) ---
    float* CP = A;  // A free after gather1; reuse first N*64 floats
    gather_kernel<64, false, false><<<g64, blk, 0, stream>>>(condition, nullptr, dinv, rowp, csr, CP, 64, 0, N);
    gemm_kernel<64, 128, true><<<gemm_grid, blk, 0, stream>>>(CP, W_c2h, b_c2h, B, 256, 128, N);

    // --- conv3: h2 = tanh(P (h @ W_h2h) + b); h2 reuses B compact ---
    gemm_kernel<256, 128, false><<<gemm_grid, blk, 0, stream>>>(B, W_h2h, nullptr, A, 128, 0, N);
    float* H2 = B;
    gather_kernel<128, true, true><<<g128, blk, 0, stream>>>(A, b_h2h, dinv, rowp, csr, H2, 128, 0, N);

    // --- conv4: z = P (h2 @ W_h2l) + b ---
    gemm_kernel<128, 64, false><<<gemm_grid, blk, 0, stream>>>(H2, W_h2l, nullptr, A, 64, 0, N);
    gather_kernel<64, false, true><<<g64, blk, 0, stream>>>(A, b_h2l, dinv, rowp, csr, out, 64, 0, N);
}

// Round 5
// 759.740 us; speedup vs baseline: 13.0075x; 1.3549x over previous
//
#include <hip/hip_runtime.h>
#include <cmath>
#include <cstdint>

// ---------------------------------------------------------------------------
// SeparateHiddenGCAEEncoder: 4 chained GCN convs, P = D^-1/2 (A+I) D^-1/2.
// Round 5: fp16 MFMA GEMMs (split-W hi/lo for precision, fp32 accum) and
// f16 activation storage so gathers move half the bytes.
// ---------------------------------------------------------------------------

typedef _Float16 f16;
typedef _Float16 f16x8 __attribute__((ext_vector_type(8)));
typedef float f32x4 __attribute__((ext_vector_type(4)));

// ---------------- CSR build ----------------
__global__ void count_zero_kernel(int* __restrict__ count, int N) {
    int i = blockIdx.x * 256 + threadIdx.x;
    if (i < N) count[i] = 0;
}

__global__ void count_kernel(const int* __restrict__ dst, int* __restrict__ count, int E) {
    int e = blockIdx.x * 256 + threadIdx.x;
    if (e < E) atomicAdd(&count[dst[e]], 1);
}

__global__ void dinv_kernel(const int* __restrict__ count, float* __restrict__ dinv, int N) {
    int i = blockIdx.x * 256 + threadIdx.x;
    if (i < N) dinv[i] = rsqrtf((float)(count[i] + 1));  // +1 self loop
}

constexpr int SCAN_VPT = 8;
constexpr int SCAN_TILE = 256 * SCAN_VPT;  // 2048

__global__ __launch_bounds__(256) void scan_partial_kernel(const int* __restrict__ count,
                                                           int* __restrict__ blocksums, int N) {
    __shared__ int red[256];
    const int t = threadIdx.x;
    int base = blockIdx.x * SCAN_TILE + t * SCAN_VPT;
    int s = 0;
#pragma unroll
    for (int i = 0; i < SCAN_VPT; ++i) {
        int idx = base + i;
        if (idx < N) s += count[idx];
    }
    red[t] = s;
    __syncthreads();
    for (int off = 128; off > 0; off >>= 1) {
        if (t < off) red[t] += red[t + off];
        __syncthreads();
    }
    if (t == 0) blocksums[blockIdx.x] = red[0];
}

__global__ __launch_bounds__(1024) void scan_blocksums_kernel(int* __restrict__ blocksums, int nb) {
    __shared__ int sh[1024];
    const int t = threadIdx.x;
    int v = (t < nb) ? blocksums[t] : 0;
    sh[t] = v;
    __syncthreads();
    for (int off = 1; off < 1024; off <<= 1) {
        int u = (t >= off) ? sh[t - off] : 0;
        __syncthreads();
        sh[t] += u;
        __syncthreads();
    }
    if (t < nb) blocksums[t] = sh[t] - v;  // exclusive
}

__global__ __launch_bounds__(256) void scan_final_kernel(const int* __restrict__ count,
                                                         const int* __restrict__ blocksums,
                                                         int* __restrict__ row_ptr,
                                                         int* __restrict__ cursor, int N) {
    __shared__ int red[256];
    const int t = threadIdx.x;
    int base = blockIdx.x * SCAN_TILE + t * SCAN_VPT;
    int vals[SCAN_VPT];
    int s = 0;
#pragma unroll
    for (int i = 0; i < SCAN_VPT; ++i) {
        int idx = base + i;
        vals[i] = (idx < N) ? count[idx] : 0;
        s += vals[i];
    }
    red[t] = s;
    __syncthreads();
    for (int off = 1; off < 256; off <<= 1) {
        int u = (t >= off) ? red[t - off] : 0;
        __syncthreads();
        red[t] += u;
        __syncthreads();
    }
    int run = red[t] - s + blocksums[blockIdx.x];
#pragma unroll
    for (int i = 0; i < SCAN_VPT; ++i) {
        int idx = base + i;
        if (idx < N) {
            row_ptr[idx] = run;
            cursor[idx] = 0;
            run += vals[i];
            if (idx == N - 1) row_ptr[N] = run;
        }
    }
}

__global__ void fill_kernel(const int* __restrict__ src, const int* __restrict__ dst,
                            const float* __restrict__ dinv, const int* __restrict__ row_ptr,
                            int* __restrict__ cursor, int2* __restrict__ csr, int E) {
    int e = blockIdx.x * 256 + threadIdx.x;
    if (e >= E) return;
    int s = src[e];
    int d = dst[e];
    int pos = row_ptr[d] + atomicAdd(&cursor[d], 1);
    float nrm = dinv[s] * dinv[d];
    csr[pos] = make_int2(s, __float_as_int(nrm));
}

// ---------------- weight prep: W[K][M] fp32 -> Wt_hi/Wt_lo [M][K] f16 -------
__global__ void wprep_kernel(const float* __restrict__ W, f16* __restrict__ wt_hi,
                             f16* __restrict__ wt_lo, int K, int M) {
    int idx = blockIdx.x * 256 + threadIdx.x;
    if (idx >= K * M) return;
    int k = idx / M, m = idx % M;
    float w = W[idx];
    f16 h = (f16)w;
    wt_hi[(size_t)m * K + k] = h;
    wt_lo[(size_t)m * K + k] = (f16)(w - (float)h);
}

// ---------------- fp32 -> f16 convert (vectorized) ----------------
__global__ void f32to16_kernel(const float* __restrict__ x, f16* __restrict__ y, int n4) {
    int i = blockIdx.x * 256 + threadIdx.x;
    if (i < n4) {
        float4 v = ((const float4*)x)[i];
        union { f16 h[4]; uint2 u; } p;
        p.h[0] = (f16)v.x; p.h[1] = (f16)v.y; p.h[2] = (f16)v.z; p.h[3] = (f16)v.w;
        ((uint2*)y)[i] = p.u;
    }
}

// ---------------- f16 MFMA GEMM: out[N,M] = X[N,K] @ (Wh+Wl) (+bias,tanh) ---
// 256 thr = 4 waves. BM=128 (wave w: rows w*32..w*32+31 = 2 x 16-row tiles),
// BK=32 (one 16x16x32 MFMA k-step per chunk). LDS rows padded to 40 f16 (80B)
// so 16-lane b128 frag reads are 2-way-bank-aliased (free). W pre-transposed
// [M][K] and hi/lo-split (f16 + remainder) to suppress weight rounding.
template <int K, int M, bool BIAS_TANH, bool X_IS_HALF>
__global__ __launch_bounds__(256) void gemm_mfma_kernel(
    const void* __restrict__ Xv, const f16* __restrict__ Wth,
    const f16* __restrict__ Wtl, const float* __restrict__ bias,
    f16* __restrict__ out, int ld, int colOff, int N) {
    constexpr int BM = 128, BK = 32, XP = 40;
    constexpr int CT = M / 16;
    __shared__ f16 xs[BM * XP];
    __shared__ f16 whs[M * XP];
    __shared__ f16 wls[M * XP];

    const int tid = threadIdx.x;
    const int lane = tid & 63;
    const int wv = tid >> 6;
    const int m16 = lane & 15;
    const int quad = lane >> 4;
    const int row0 = blockIdx.x * BM;

    f32x4 acc[2][CT];
#pragma unroll
    for (int rt = 0; rt < 2; ++rt)
#pragma unroll
        for (int ct = 0; ct < CT; ++ct) acc[rt][ct] = (f32x4){0.f, 0.f, 0.f, 0.f};

    for (int k0 = 0; k0 < K; k0 += BK) {
        if (X_IS_HALF) {
            const f16* X = (const f16*)Xv;
#pragma unroll
            for (int i = 0; i < 2; ++i) {
                int c = i * 256 + tid;
                int r = c >> 2, ko = (c & 3) * 8;
                uint4 v = make_uint4(0u, 0u, 0u, 0u);
                if (row0 + r < N) v = *(const uint4*)(X + (size_t)(row0 + r) * K + k0 + ko);
                *(uint4*)(&xs[r * XP + ko]) = v;
            }
        } else {
            const float* X = (const float*)Xv;
#pragma unroll
            for (int i = 0; i < 4; ++i) {
                int c = i * 256 + tid;
                int r = c >> 3, kq = (c & 7) * 4;
                float4 v = make_float4(0.f, 0.f, 0.f, 0.f);
                if (row0 + r < N) v = *(const float4*)(X + (size_t)(row0 + r) * K + k0 + kq);
                union { f16 h[4]; uint2 u; } p;
                p.h[0] = (f16)v.x; p.h[1] = (f16)v.y; p.h[2] = (f16)v.z; p.h[3] = (f16)v.w;
                *(uint2*)(&xs[r * XP + kq]) = p.u;
            }
        }
#pragma unroll
        for (int i = 0; i < (M * 4) / 256; ++i) {
            int c = i * 256 + tid;
            int n = c >> 2, ko = (c & 3) * 8;
            *(uint4*)(&whs[n * XP + ko]) = *(const uint4*)(Wth + (size_t)n * K + k0 + ko);
            *(uint4*)(&wls[n * XP + ko]) = *(const uint4*)(Wtl + (size_t)n * K + k0 + ko);
        }
        __syncthreads();

        f16x8 a0 = *(const f16x8*)(&xs[(wv * 32 + 0 + m16) * XP + quad * 8]);
        f16x8 a1 = *(const f16x8*)(&xs[(wv * 32 + 16 + m16) * XP + quad * 8]);
#pragma unroll
        for (int ct = 0; ct < CT; ++ct) {
            f16x8 bh = *(const f16x8*)(&whs[(ct * 16 + m16) * XP + quad * 8]);
            f16x8 bl = *(const f16x8*)(&wls[(ct * 16 + m16) * XP + quad * 8]);
            acc[0][ct] = __builtin_amdgcn_mfma_f32_16x16x32_f16(a0, bh, acc[0][ct], 0, 0, 0);
            acc[0][ct] = __builtin_amdgcn_mfma_f32_16x16x32_f16(a0, bl, acc[0][ct], 0, 0, 0);
            acc[1][ct] = __builtin_amdgcn_mfma_f32_16x16x32_f16(a1, bh, acc[1][ct], 0, 0, 0);
            acc[1][ct] = __builtin_amdgcn_mfma_f32_16x16x32_f16(a1, bl, acc[1][ct], 0, 0, 0);
        }
        __syncthreads();
    }

    float brs[CT];
    if (BIAS_TANH) {
#pragma unroll
        for (int ct = 0; ct < CT; ++ct) brs[ct] = bias[ct * 16 + m16];
    }

    // C/D layout: col = lane&15, row(within 16) = quad*4 + reg
#pragma unroll
    for (int rt = 0; rt < 2; ++rt) {
#pragma unroll
        for (int r = 0; r < 4; ++r) {
            int row = row0 + wv * 32 + rt * 16 + quad * 4 + r;
            if (row < N) {
                f16* op = out + (size_t)row * ld + colOff + m16;
#pragma unroll
                for (int ct = 0; ct < CT; ++ct) {
                    float v = acc[rt][ct][r];
                    if (BIAS_TANH) v = tanhf(v + brs[ct]);
                    op[ct * 16] = (f16)v;
                }
            }
        }
    }
}

// ---------------- f16 gather: out[i] = (tanh?)((b?) + xl[i]*dinv^2 + sum xl[j]*nrm)
template <int M, bool TANH, bool HAS_BIAS, bool OUT_F32>
__global__ __launch_bounds__(256) void gather_h_kernel(
    const f16* __restrict__ xl, const float* __restrict__ b,
    const float* __restrict__ dinv, const int* __restrict__ row_ptr,
    const int2* __restrict__ csr, void* __restrict__ outv,
    int ld, int colOff, int N) {
    constexpr int TPN = M / 8;  // threads per node (8 f16 = 16B each)
    int gid = blockIdx.x * 256 + threadIdx.x;
    int node = gid / TPN;
    int t = gid % TPN;
    if (node >= N) return;

    float di = dinv[node];
    float self = di * di;
    f16x8 x = *(const f16x8*)(xl + (size_t)node * M + t * 8);
    float acc[8];
#pragma unroll
    for (int j = 0; j < 8; ++j) acc[j] = (float)x[j] * self;
    if (HAS_BIAS) {
        float4 b0 = *(const float4*)(b + t * 8);
        float4 b1 = *(const float4*)(b + t * 8 + 4);
        acc[0] += b0.x; acc[1] += b0.y; acc[2] += b0.z; acc[3] += b0.w;
        acc[4] += b1.x; acc[5] += b1.y; acc[6] += b1.z; acc[7] += b1.w;
    }

    int p = row_ptr[node];
    const int p1 = row_ptr[node + 1];
    for (; p + 2 <= p1; p += 2) {  // 2 rows in flight
        int2 e0 = csr[p];
        int2 e1 = csr[p + 1];
        f16x8 v0 = *(const f16x8*)(xl + (size_t)e0.x * M + t * 8);
        f16x8 v1 = *(const f16x8*)(xl + (size_t)e1.x * M + t * 8);
        float n0 = __int_as_float(e0.y);
        float n1 = __int_as_float(e1.y);
#pragma unroll
        for (int j = 0; j < 8; ++j) acc[j] += (float)v0[j] * n0 + (float)v1[j] * n1;
    }
    if (p < p1) {
        int2 e0 = csr[p];
        f16x8 v0 = *(const f16x8*)(xl + (size_t)e0.x * M + t * 8);
        float n0 = __int_as_float(e0.y);
#pragma unroll
        for (int j = 0; j < 8; ++j) acc[j] += (float)v0[j] * n0;
    }

    if (TANH) {
#pragma unroll
        for (int j = 0; j < 8; ++j) acc[j] = tanhf(acc[j]);
    }

    if (OUT_F32) {
        float* op = (float*)outv + (size_t)node * ld + colOff + t * 8;
        *(float4*)op = make_float4(acc[0], acc[1], acc[2], acc[3]);
        *(float4*)(op + 4) = make_float4(acc[4], acc[5], acc[6], acc[7]);
    } else {
        f16x8 o;
#pragma unroll
        for (int j = 0; j < 8; ++j) o[j] = (f16)acc[j];
        *(f16x8*)((f16*)outv + (size_t)node * ld + colOff + t * 8) = o;
    }
}

// ---------------------------------------------------------------------------
extern "C" void kernel_launch(void* const* d_in, const int* in_sizes, int n_in,
                              void* d_out, int out_size, void* d_ws, size_t ws_size,
                              hipStream_t stream) {
    const int FD = 256;

    const float* feature   = (const float*)d_in[0];
    const float* condition = (const float*)d_in[1];
    const int*   edge      = (const int*)d_in[2];
    const float* W_f2h = (const float*)d_in[3];
    const float* b_f2h = (const float*)d_in[4];
    const float* W_c2h = (const float*)d_in[5];
    const float* b_c2h = (const float*)d_in[6];
    const float* W_h2h = (const float*)d_in[7];
    const float* b_h2h = (const float*)d_in[8];
    const float* W_h2l = (const float*)d_in[9];
    const float* b_h2l = (const float*)d_in[10];
    float* out = (float*)d_out;

    const int N = in_sizes[0] / FD;   // 100000
    const int E = in_sizes[2] / 2;    // 1600000
    const int* src = edge;
    const int* dst = edge + E;

    // workspace layout
    float* ws_f   = (float*)d_ws;
    float* dinv   = ws_f;                                // N floats
    int*   count  = (int*)(ws_f + N);                    // N ints
    int*   rowp   = count + N;                           // N+1 ints
    int*   cursor = rowp + N + 1;                        // N ints
    int*   bsums  = cursor + N;                          // 1024 ints
    int2*  csr    = (int2*)(((uintptr_t)(bsums + 1024) + 15) & ~(uintptr_t)15);  // E int2
    f16*   A_h    = (f16*)(csr + E);                     // N*128 f16 (xl scratch)
    f16*   B_h    = A_h + (size_t)N * 128;               // N*256 f16 (h; reused as H2)
    f16*   cond_h = B_h + (size_t)N * 256;               // N*64  f16
    f16*   wt1h   = cond_h + (size_t)N * 64;             // 128*256
    f16*   wt1l   = wt1h + 128 * 256;
    f16*   wt2h   = wt1l + 128 * 256;                    // 128*64
    f16*   wt2l   = wt2h + 128 * 64;
    f16*   wt3h   = wt2l + 128 * 64;                     // 128*256
    f16*   wt3l   = wt3h + 128 * 256;
    f16*   wt4h   = wt3l + 128 * 256;                    // 64*128
    f16*   wt4l   = wt4h + 64 * 128;

    const int TB = 256;
    dim3 blk(TB);
    const int nScanBlocks = (N + SCAN_TILE - 1) / SCAN_TILE;  // 49

    // --- weight prep + condition convert ---
    wprep_kernel<<<(256 * 128 + TB - 1) / TB, blk, 0, stream>>>(W_f2h, wt1h, wt1l, 256, 128);
    wprep_kernel<<<(64 * 128 + TB - 1) / TB, blk, 0, stream>>>(W_c2h, wt2h, wt2l, 64, 128);
    wprep_kernel<<<(256 * 128 + TB - 1) / TB, blk, 0, stream>>>(W_h2h, wt3h, wt3l, 256, 128);
    wprep_kernel<<<(128 * 64 + TB - 1) / TB, blk, 0, stream>>>(W_h2l, wt4h, wt4l, 128, 64);
    f32to16_kernel<<<(N * 16 + TB - 1) / TB, blk, 0, stream>>>(condition, cond_h, N * 16);

    // --- CSR build + norms ---
    count_zero_kernel<<<(N + TB - 1) / TB, blk, 0, stream>>>(count, N);
    count_kernel<<<(E + TB - 1) / TB, blk, 0, stream>>>(dst, count, E);
    dinv_kernel<<<(N + TB - 1) / TB, blk, 0, stream>>>(count, dinv, N);
    scan_partial_kernel<<<nScanBlocks, blk, 0, stream>>>(count, bsums, N);
    scan_blocksums_kernel<<<1, 1024, 0, stream>>>(bsums, nScanBlocks);
    scan_final_kernel<<<nScanBlocks, blk, 0, stream>>>(count, bsums, rowp, cursor, N);
    fill_kernel<<<(E + TB - 1) / TB, blk, 0, stream>>>(src, dst, dinv, rowp, cursor, csr, E);

    const int gemm_grid = (N + 127) / 128;               // 782
    const int g128 = (N * 16 + TB - 1) / TB;             // gather grid, M=128 (TPN=16)
    const int g64  = (N * 8 + TB - 1) / TB;              // gather grid, M=64  (TPN=8)

    // --- conv1: f2h = tanh(P(feature@W)+b) -> B_h[:, 0:128] ---
    gemm_mfma_kernel<256, 128, false, false><<<gemm_grid, blk, 0, stream>>>(
        feature, wt1h, wt1l, nullptr, A_h, 128, 0, N);
    gather_h_kernel<128, true, true, false><<<g128, blk, 0, stream>>>(
        A_h, b_f2h, dinv, rowp, csr, B_h, 256, 0, N);

    // --- conv2 (reordered): cprop = P*condition (f16, 64-wide), then tanh(cprop@W+b) ---
    gather_h_kernel<64, false, false, false><<<g64, blk, 0, stream>>>(
        cond_h, nullptr, dinv, rowp, csr, A_h, 64, 0, N);
    gemm_mfma_kernel<64, 128, true, true><<<gemm_grid, blk, 0, stream>>>(
        A_h, wt2h, wt2l, b_c2h, B_h, 256, 128, N);

    // --- conv3: h2 = tanh(P (h @ W_h2h) + b); H2 reuses B_h compact N x 128 ---
    gemm_mfma_kernel<256, 128, false, true><<<gemm_grid, blk, 0, stream>>>(
        B_h, wt3h, wt3l, nullptr, A_h, 128, 0, N);
    gather_h_kernel<128, true, true, false><<<g128, blk, 0, stream>>>(
        A_h, b_h2h, dinv, rowp, csr, B_h, 128, 0, N);

    // --- conv4: z = P (h2 @ W_h2l) + b -> fp32 out ---
    gemm_mfma_kernel<128, 64, false, true><<<gemm_grid, blk, 0, stream>>>(
        B_h, wt4h, wt4l, nullptr, A_h, 64, 0, N);
    gather_h_kernel<64, false, true, true><<<g64, blk, 0, stream>>>(
        A_h, b_h2l, dinv, rowp, csr, out, 64, 0, N);
}

// Round 6
// 757.245 us; speedup vs baseline: 13.0503x; 1.0033x over previous
//
#include <hip/hip_runtime.h>
#include <cmath>
#include <cstdint>

// ---------------------------------------------------------------------------
// SeparateHiddenGCAEEncoder: 4 chained GCN convs, P = D^-1/2 (A+I) D^-1/2.
// Round 6: GEMM restructured so each wave owns an M/4 column strip and all 8
// row tiles -> B-fragment LDS reads amortized 8x (was the bottleneck).
// Gather neighbor loop unrolled x4 for memory-level parallelism.
// ---------------------------------------------------------------------------

typedef _Float16 f16;
typedef _Float16 f16x8 __attribute__((ext_vector_type(8)));
typedef float f32x4 __attribute__((ext_vector_type(4)));

// ---------------- CSR build ----------------
__global__ void count_zero_kernel(int* __restrict__ count, int N) {
    int i = blockIdx.x * 256 + threadIdx.x;
    if (i < N) count[i] = 0;
}

__global__ void count_kernel(const int* __restrict__ dst, int* __restrict__ count, int E) {
    int e = blockIdx.x * 256 + threadIdx.x;
    if (e < E) atomicAdd(&count[dst[e]], 1);
}

__global__ void dinv_kernel(const int* __restrict__ count, float* __restrict__ dinv, int N) {
    int i = blockIdx.x * 256 + threadIdx.x;
    if (i < N) dinv[i] = rsqrtf((float)(count[i] + 1));  // +1 self loop
}

constexpr int SCAN_VPT = 8;
constexpr int SCAN_TILE = 256 * SCAN_VPT;  // 2048

__global__ __launch_bounds__(256) void scan_partial_kernel(const int* __restrict__ count,
                                                           int* __restrict__ blocksums, int N) {
    __shared__ int red[256];
    const int t = threadIdx.x;
    int base = blockIdx.x * SCAN_TILE + t * SCAN_VPT;
    int s = 0;
#pragma unroll
    for (int i = 0; i < SCAN_VPT; ++i) {
        int idx = base + i;
        if (idx < N) s += count[idx];
    }
    red[t] = s;
    __syncthreads();
    for (int off = 128; off > 0; off >>= 1) {
        if (t < off) red[t] += red[t + off];
        __syncthreads();
    }
    if (t == 0) blocksums[blockIdx.x] = red[0];
}

__global__ __launch_bounds__(1024) void scan_blocksums_kernel(int* __restrict__ blocksums, int nb) {
    __shared__ int sh[1024];
    const int t = threadIdx.x;
    int v = (t < nb) ? blocksums[t] : 0;
    sh[t] = v;
    __syncthreads();
    for (int off = 1; off < 1024; off <<= 1) {
        int u = (t >= off) ? sh[t - off] : 0;
        __syncthreads();
        sh[t] += u;
        __syncthreads();
    }
    if (t < nb) blocksums[t] = sh[t] - v;  // exclusive
}

__global__ __launch_bounds__(256) void scan_final_kernel(const int* __restrict__ count,
                                                         const int* __restrict__ blocksums,
                                                         int* __restrict__ row_ptr,
                                                         int* __restrict__ cursor, int N) {
    __shared__ int red[256];
    const int t = threadIdx.x;
    int base = blockIdx.x * SCAN_TILE + t * SCAN_VPT;
    int vals[SCAN_VPT];
    int s = 0;
#pragma unroll
    for (int i = 0; i < SCAN_VPT; ++i) {
        int idx = base + i;
        vals[i] = (idx < N) ? count[idx] : 0;
        s += vals[i];
    }
    red[t] = s;
    __syncthreads();
    for (int off = 1; off < 256; off <<= 1) {
        int u = (t >= off) ? red[t - off] : 0;
        __syncthreads();
        red[t] += u;
        __syncthreads();
    }
    int run = red[t] - s + blocksums[blockIdx.x];
#pragma unroll
    for (int i = 0; i < SCAN_VPT; ++i) {
        int idx = base + i;
        if (idx < N) {
            row_ptr[idx] = run;
            cursor[idx] = 0;
            run += vals[i];
            if (idx == N - 1) row_ptr[N] = run;
        }
    }
}

__global__ void fill_kernel(const int* __restrict__ src, const int* __restrict__ dst,
                            const float* __restrict__ dinv, const int* __restrict__ row_ptr,
                            int* __restrict__ cursor, int2* __restrict__ csr, int E) {
    int e = blockIdx.x * 256 + threadIdx.x;
    if (e >= E) return;
    int s = src[e];
    int d = dst[e];
    int pos = row_ptr[d] + atomicAdd(&cursor[d], 1);
    float nrm = dinv[s] * dinv[d];
    csr[pos] = make_int2(s, __float_as_int(nrm));
}

// ---------------- weight prep: W[K][M] fp32 -> Wt_hi/Wt_lo [M][K] f16 -------
__global__ void wprep_kernel(const float* __restrict__ W, f16* __restrict__ wt_hi,
                             f16* __restrict__ wt_lo, int K, int M) {
    int idx = blockIdx.x * 256 + threadIdx.x;
    if (idx >= K * M) return;
    int k = idx / M, m = idx % M;
    float w = W[idx];
    f16 h = (f16)w;
    wt_hi[(size_t)m * K + k] = h;
    wt_lo[(size_t)m * K + k] = (f16)(w - (float)h);
}

// ---------------- fp32 -> f16 convert (vectorized) ----------------
__global__ void f32to16_kernel(const float* __restrict__ x, f16* __restrict__ y, int n4) {
    int i = blockIdx.x * 256 + threadIdx.x;
    if (i < n4) {
        float4 v = ((const float4*)x)[i];
        union { f16 h[4]; uint2 u; } p;
        p.h[0] = (f16)v.x; p.h[1] = (f16)v.y; p.h[2] = (f16)v.z; p.h[3] = (f16)v.w;
        ((uint2*)y)[i] = p.u;
    }
}

// ---------------- f16 MFMA GEMM: out[N,M] = X[N,K] @ (Wh+Wl) (+bias,tanh) ---
// 256 thr = 4 waves. BM=128, BK=32. Each wave owns an SW=M/4 column strip and
// iterates all 8 row tiles -> per k0: B-frag reads = 2*CT, A reads = 8,
// MFMAs = 8*CT*2 (hi+lo split). W pre-transposed [M][K], hi/lo split.
template <int K, int M, bool BIAS_TANH, bool X_IS_HALF>
__global__ __launch_bounds__(256) void gemm_mfma_kernel(
    const void* __restrict__ Xv, const f16* __restrict__ Wth,
    const f16* __restrict__ Wtl, const float* __restrict__ bias,
    f16* __restrict__ out, int ld, int colOff, int N) {
    constexpr int BM = 128, BK = 32, XP = 40;
    constexpr int SW = M / 4;    // column strip per wave (32 or 16)
    constexpr int CT = SW / 16;  // 16-col tiles per wave (2 or 1)
    constexpr int RT = BM / 16;  // 8 row tiles
    __shared__ f16 xs[BM * XP];
    __shared__ f16 whs[M * XP];
    __shared__ f16 wls[M * XP];

    const int tid = threadIdx.x;
    const int lane = tid & 63;
    const int wv = tid >> 6;
    const int m16 = lane & 15;
    const int quad = lane >> 4;
    const int row0 = blockIdx.x * BM;

    f32x4 acc[RT][CT];
#pragma unroll
    for (int rt = 0; rt < RT; ++rt)
#pragma unroll
        for (int ct = 0; ct < CT; ++ct) acc[rt][ct] = (f32x4){0.f, 0.f, 0.f, 0.f};

    for (int k0 = 0; k0 < K; k0 += BK) {
        if (X_IS_HALF) {
            const f16* X = (const f16*)Xv;
#pragma unroll
            for (int i = 0; i < 2; ++i) {
                int c = i * 256 + tid;
                int r = c >> 2, ko = (c & 3) * 8;
                uint4 v = make_uint4(0u, 0u, 0u, 0u);
                if (row0 + r < N) v = *(const uint4*)(X + (size_t)(row0 + r) * K + k0 + ko);
                *(uint4*)(&xs[r * XP + ko]) = v;
            }
        } else {
            const float* X = (const float*)Xv;
#pragma unroll
            for (int i = 0; i < 4; ++i) {
                int c = i * 256 + tid;
                int r = c >> 3, kq = (c & 7) * 4;
                float4 v = make_float4(0.f, 0.f, 0.f, 0.f);
                if (row0 + r < N) v = *(const float4*)(X + (size_t)(row0 + r) * K + k0 + kq);
                union { f16 h[4]; uint2 u; } p;
                p.h[0] = (f16)v.x; p.h[1] = (f16)v.y; p.h[2] = (f16)v.z; p.h[3] = (f16)v.w;
                *(uint2*)(&xs[r * XP + kq]) = p.u;
            }
        }
#pragma unroll
        for (int i = 0; i < (M * 4) / 256; ++i) {
            int c = i * 256 + tid;
            int n = c >> 2, ko = (c & 3) * 8;
            *(uint4*)(&whs[n * XP + ko]) = *(const uint4*)(Wth + (size_t)n * K + k0 + ko);
            *(uint4*)(&wls[n * XP + ko]) = *(const uint4*)(Wtl + (size_t)n * K + k0 + ko);
        }
        __syncthreads();

        f16x8 bh[CT], bl[CT];
#pragma unroll
        for (int ct = 0; ct < CT; ++ct) {
            bh[ct] = *(const f16x8*)(&whs[(wv * SW + ct * 16 + m16) * XP + quad * 8]);
            bl[ct] = *(const f16x8*)(&wls[(wv * SW + ct * 16 + m16) * XP + quad * 8]);
        }
#pragma unroll
        for (int rt = 0; rt < RT; ++rt) {
            f16x8 a = *(const f16x8*)(&xs[(rt * 16 + m16) * XP + quad * 8]);
#pragma unroll
            for (int ct = 0; ct < CT; ++ct) {
                acc[rt][ct] = __builtin_amdgcn_mfma_f32_16x16x32_f16(a, bh[ct], acc[rt][ct], 0, 0, 0);
                acc[rt][ct] = __builtin_amdgcn_mfma_f32_16x16x32_f16(a, bl[ct], acc[rt][ct], 0, 0, 0);
            }
        }
        __syncthreads();
    }

    float brs[CT];
    if (BIAS_TANH) {
#pragma unroll
        for (int ct = 0; ct < CT; ++ct) brs[ct] = bias[wv * SW + ct * 16 + m16];
    }

    // C/D layout: col = lane&15, row(within 16) = quad*4 + reg
#pragma unroll
    for (int rt = 0; rt < RT; ++rt) {
#pragma unroll
        for (int r = 0; r < 4; ++r) {
            int row = row0 + rt * 16 + quad * 4 + r;
            if (row < N) {
                f16* op = out + (size_t)row * ld + colOff + wv * SW + m16;
#pragma unroll
                for (int ct = 0; ct < CT; ++ct) {
                    float v = acc[rt][ct][r];
                    if (BIAS_TANH) v = tanhf(v + brs[ct]);
                    op[ct * 16] = (f16)v;
                }
            }
        }
    }
}

// ---------------- f16 gather: out[i] = (tanh?)((b?) + xl[i]*dinv^2 + sum xl[j]*nrm)
template <int M, bool TANH, bool HAS_BIAS, bool OUT_F32>
__global__ __launch_bounds__(256) void gather_h_kernel(
    const f16* __restrict__ xl, const float* __restrict__ b,
    const float* __restrict__ dinv, const int* __restrict__ row_ptr,
    const int2* __restrict__ csr, void* __restrict__ outv,
    int ld, int colOff, int N) {
    constexpr int TPN = M / 8;  // threads per node (8 f16 = 16B each)
    int gid = blockIdx.x * 256 + threadIdx.x;
    int node = gid / TPN;
    int t = gid % TPN;
    if (node >= N) return;

    float di = dinv[node];
    float self = di * di;
    f16x8 x = *(const f16x8*)(xl + (size_t)node * M + t * 8);
    float acc[8];
#pragma unroll
    for (int j = 0; j < 8; ++j) acc[j] = (float)x[j] * self;
    if (HAS_BIAS) {
        float4 b0 = *(const float4*)(b + t * 8);
        float4 b1 = *(const float4*)(b + t * 8 + 4);
        acc[0] += b0.x; acc[1] += b0.y; acc[2] += b0.z; acc[3] += b0.w;
        acc[4] += b1.x; acc[5] += b1.y; acc[6] += b1.z; acc[7] += b1.w;
    }

    int p = row_ptr[node];
    const int p1 = row_ptr[node + 1];
    for (; p + 4 <= p1; p += 4) {  // 4 rows in flight
        int2 e0 = csr[p];
        int2 e1 = csr[p + 1];
        int2 e2 = csr[p + 2];
        int2 e3 = csr[p + 3];
        f16x8 v0 = *(const f16x8*)(xl + (size_t)e0.x * M + t * 8);
        f16x8 v1 = *(const f16x8*)(xl + (size_t)e1.x * M + t * 8);
        f16x8 v2 = *(const f16x8*)(xl + (size_t)e2.x * M + t * 8);
        f16x8 v3 = *(const f16x8*)(xl + (size_t)e3.x * M + t * 8);
        float n0 = __int_as_float(e0.y);
        float n1 = __int_as_float(e1.y);
        float n2 = __int_as_float(e2.y);
        float n3 = __int_as_float(e3.y);
#pragma unroll
        for (int j = 0; j < 8; ++j)
            acc[j] += ((float)v0[j] * n0 + (float)v1[j] * n1) +
                      ((float)v2[j] * n2 + (float)v3[j] * n3);
    }
    for (; p < p1; ++p) {
        int2 e0 = csr[p];
        f16x8 v0 = *(const f16x8*)(xl + (size_t)e0.x * M + t * 8);
        float n0 = __int_as_float(e0.y);
#pragma unroll
        for (int j = 0; j < 8; ++j) acc[j] += (float)v0[j] * n0;
    }

    if (TANH) {
#pragma unroll
        for (int j = 0; j < 8; ++j) acc[j] = tanhf(acc[j]);
    }

    if (OUT_F32) {
        float* op = (float*)outv + (size_t)node * ld + colOff + t * 8;
        *(float4*)op = make_float4(acc[0], acc[1], acc[2], acc[3]);
        *(float4*)(op + 4) = make_float4(acc[4], acc[5], acc[6], acc[7]);
    } else {
        f16x8 o;
#pragma unroll
        for (int j = 0; j < 8; ++j) o[j] = (f16)acc[j];
        *(f16x8*)((f16*)outv + (size_t)node * ld + colOff + t * 8) = o;
    }
}

// ---------------------------------------------------------------------------
extern "C" void kernel_launch(void* const* d_in, const int* in_sizes, int n_in,
                              void* d_out, int out_size, void* d_ws, size_t ws_size,
                              hipStream_t stream) {
    const int FD = 256;

    const float* feature   = (const float*)d_in[0];
    const float* condition = (const float*)d_in[1];
    const int*   edge      = (const int*)d_in[2];
    const float* W_f2h = (const float*)d_in[3];
    const float* b_f2h = (const float*)d_in[4];
    const float* W_c2h = (const float*)d_in[5];
    const float* b_c2h = (const float*)d_in[6];
    const float* W_h2h = (const float*)d_in[7];
    const float* b_h2h = (const float*)d_in[8];
    const float* W_h2l = (const float*)d_in[9];
    const float* b_h2l = (const float*)d_in[10];
    float* out = (float*)d_out;

    const int N = in_sizes[0] / FD;   // 100000
    const int E = in_sizes[2] / 2;    // 1600000
    const int* src = edge;
    const int* dst = edge + E;

    // workspace layout
    float* ws_f   = (float*)d_ws;
    float* dinv   = ws_f;                                // N floats
    int*   count  = (int*)(ws_f + N);                    // N ints
    int*   rowp   = count + N;                           // N+1 ints
    int*   cursor = rowp + N + 1;                        // N ints
    int*   bsums  = cursor + N;                          // 1024 ints
    int2*  csr    = (int2*)(((uintptr_t)(bsums + 1024) + 15) & ~(uintptr_t)15);  // E int2
    f16*   A_h    = (f16*)(csr + E);                     // N*128 f16 (xl scratch)
    f16*   B_h    = A_h + (size_t)N * 128;               // N*256 f16 (h; reused as H2)
    f16*   cond_h = B_h + (size_t)N * 256;               // N*64  f16
    f16*   wt1h   = cond_h + (size_t)N * 64;             // 128*256
    f16*   wt1l   = wt1h + 128 * 256;
    f16*   wt2h   = wt1l + 128 * 256;                    // 128*64
    f16*   wt2l   = wt2h + 128 * 64;
    f16*   wt3h   = wt2l + 128 * 64;                     // 128*256
    f16*   wt3l   = wt3h + 128 * 256;
    f16*   wt4h   = wt3l + 128 * 256;                    // 64*128
    f16*   wt4l   = wt4h + 64 * 128;

    const int TB = 256;
    dim3 blk(TB);
    const int nScanBlocks = (N + SCAN_TILE - 1) / SCAN_TILE;  // 49

    // --- weight prep + condition convert ---
    wprep_kernel<<<(256 * 128 + TB - 1) / TB, blk, 0, stream>>>(W_f2h, wt1h, wt1l, 256, 128);
    wprep_kernel<<<(64 * 128 + TB - 1) / TB, blk, 0, stream>>>(W_c2h, wt2h, wt2l, 64, 128);
    wprep_kernel<<<(256 * 128 + TB - 1) / TB, blk, 0, stream>>>(W_h2h, wt3h, wt3l, 256, 128);
    wprep_kernel<<<(128 * 64 + TB - 1) / TB, blk, 0, stream>>>(W_h2l, wt4h, wt4l, 128, 64);
    f32to16_kernel<<<(N * 16 + TB - 1) / TB, blk, 0, stream>>>(condition, cond_h, N * 16);

    // --- CSR build + norms ---
    count_zero_kernel<<<(N + TB - 1) / TB, blk, 0, stream>>>(count, N);
    count_kernel<<<(E + TB - 1) / TB, blk, 0, stream>>>(dst, count, E);
    dinv_kernel<<<(N + TB - 1) / TB, blk, 0, stream>>>(count, dinv, N);
    scan_partial_kernel<<<nScanBlocks, blk, 0, stream>>>(count, bsums, N);
    scan_blocksums_kernel<<<1, 1024, 0, stream>>>(bsums, nScanBlocks);
    scan_final_kernel<<<nScanBlocks, blk, 0, stream>>>(count, bsums, rowp, cursor, N);
    fill_kernel<<<(E + TB - 1) / TB, blk, 0, stream>>>(src, dst, dinv, rowp, cursor, csr, E);

    const int gemm_grid = (N + 127) / 128;               // 782
    const int g128 = (N * 16 + TB - 1) / TB;             // gather grid, M=128 (TPN=16)
    const int g64  = (N * 8 + TB - 1) / TB;              // gather grid, M=64  (TPN=8)

    // --- conv1: f2h = tanh(P(feature@W)+b) -> B_h[:, 0:128] ---
    gemm_mfma_kernel<256, 128, false, false><<<gemm_grid, blk, 0, stream>>>(
        feature, wt1h, wt1l, nullptr, A_h, 128, 0, N);
    gather_h_kernel<128, true, true, false><<<g128, blk, 0, stream>>>(
        A_h, b_f2h, dinv, rowp, csr, B_h, 256, 0, N);

    // --- conv2 (reordered): cprop = P*condition (f16, 64-wide), then tanh(cprop@W+b) ---
    gather_h_kernel<64, false, false, false><<<g64, blk, 0, stream>>>(
        cond_h, nullptr, dinv, rowp, csr, A_h, 64, 0, N);
    gemm_mfma_kernel<64, 128, true, true><<<gemm_grid, blk, 0, stream>>>(
        A_h, wt2h, wt2l, b_c2h, B_h, 256, 128, N);

    // --- conv3: h2 = tanh(P (h @ W_h2h) + b); H2 reuses B_h compact N x 128 ---
    gemm_mfma_kernel<256, 128, false, true><<<gemm_grid, blk, 0, stream>>>(
        B_h, wt3h, wt3l, nullptr, A_h, 128, 0, N);
    gather_h_kernel<128, true, true, false><<<g128, blk, 0, stream>>>(
        A_h, b_h2h, dinv, rowp, csr, B_h, 128, 0, N);

    // --- conv4: z = P (h2 @ W_h2l) + b -> fp32 out ---
    gemm_mfma_kernel<128, 64, false, true><<<gemm_grid, blk, 0, stream>>>(
        B_h, wt4h, wt4l, nullptr, A_h, 64, 0, N);
    gather_h_kernel<64, false, true, true><<<g64, blk, 0, stream>>>(
        A_h, b_h2l, dinv, rowp, csr, out, 64, 0, N);
}

// Round 8
// 736.087 us; speedup vs baseline: 13.4255x; 1.0287x over previous
//
#include <hip/hip_runtime.h>
#include <cmath>
#include <cstdint>

// ---------------------------------------------------------------------------
// SeparateHiddenGCAEEncoder: 4 chained GCN convs, P = D^-1/2 (A+I) D^-1/2.
// Round 8 (= round 7 intent, compile-fixed): CSR fill without atomics (rank
// captured during count pass); non-temporal stores via clang ext_vector types
// (HIP float4/uint4 are classes -> rejected by __builtin_nontemporal_store).
// ---------------------------------------------------------------------------

typedef _Float16 f16;
typedef _Float16 f16x8 __attribute__((ext_vector_type(8)));
typedef float f32x4 __attribute__((ext_vector_type(4)));
typedef unsigned int u32x4 __attribute__((ext_vector_type(4)));

// ---------------- CSR build ----------------
__global__ void count_zero_kernel(int* __restrict__ count, int N) {
    int i = blockIdx.x * 256 + threadIdx.x;
    if (i < N) count[i] = 0;
}

// count + per-edge rank (old value of the counter) in one atomic pass
__global__ void count_rank_kernel(const int* __restrict__ dst, int* __restrict__ count,
                                  int* __restrict__ rank, int E) {
    int e = blockIdx.x * 256 + threadIdx.x;
    if (e < E) rank[e] = atomicAdd(&count[dst[e]], 1);
}

__global__ void dinv_kernel(const int* __restrict__ count, float* __restrict__ dinv, int N) {
    int i = blockIdx.x * 256 + threadIdx.x;
    if (i < N) dinv[i] = rsqrtf((float)(count[i] + 1));  // +1 self loop
}

constexpr int SCAN_VPT = 8;
constexpr int SCAN_TILE = 256 * SCAN_VPT;  // 2048

__global__ __launch_bounds__(256) void scan_partial_kernel(const int* __restrict__ count,
                                                           int* __restrict__ blocksums, int N) {
    __shared__ int red[256];
    const int t = threadIdx.x;
    int base = blockIdx.x * SCAN_TILE + t * SCAN_VPT;
    int s = 0;
#pragma unroll
    for (int i = 0; i < SCAN_VPT; ++i) {
        int idx = base + i;
        if (idx < N) s += count[idx];
    }
    red[t] = s;
    __syncthreads();
    for (int off = 128; off > 0; off >>= 1) {
        if (t < off) red[t] += red[t + off];
        __syncthreads();
    }
    if (t == 0) blocksums[blockIdx.x] = red[0];
}

__global__ __launch_bounds__(1024) void scan_blocksums_kernel(int* __restrict__ blocksums, int nb) {
    __shared__ int sh[1024];
    const int t = threadIdx.x;
    int v = (t < nb) ? blocksums[t] : 0;
    sh[t] = v;
    __syncthreads();
    for (int off = 1; off < 1024; off <<= 1) {
        int u = (t >= off) ? sh[t - off] : 0;
        __syncthreads();
        sh[t] += u;
        __syncthreads();
    }
    if (t < nb) blocksums[t] = sh[t] - v;  // exclusive
}

__global__ __launch_bounds__(256) void scan_final_kernel(const int* __restrict__ count,
                                                         const int* __restrict__ blocksums,
                                                         int* __restrict__ row_ptr, int N) {
    __shared__ int red[256];
    const int t = threadIdx.x;
    int base = blockIdx.x * SCAN_TILE + t * SCAN_VPT;
    int vals[SCAN_VPT];
    int s = 0;
#pragma unroll
    for (int i = 0; i < SCAN_VPT; ++i) {
        int idx = base + i;
        vals[i] = (idx < N) ? count[idx] : 0;
        s += vals[i];
    }
    red[t] = s;
    __syncthreads();
    for (int off = 1; off < 256; off <<= 1) {
        int u = (t >= off) ? red[t - off] : 0;
        __syncthreads();
        red[t] += u;
        __syncthreads();
    }
    int run = red[t] - s + blocksums[blockIdx.x];
#pragma unroll
    for (int i = 0; i < SCAN_VPT; ++i) {
        int idx = base + i;
        if (idx < N) {
            row_ptr[idx] = run;
            run += vals[i];
            if (idx == N - 1) row_ptr[N] = run;
        }
    }
}

// atomic-free fill using precomputed ranks; NT store (csr is consumed later
// as a sequential stream -- keep it out of L2)
__global__ void fill_kernel(const int* __restrict__ src, const int* __restrict__ dst,
                            const int* __restrict__ rank, const float* __restrict__ dinv,
                            const int* __restrict__ row_ptr, long long* __restrict__ csr, int E) {
    int e = blockIdx.x * 256 + threadIdx.x;
    if (e >= E) return;
    int s = src[e];
    int d = dst[e];
    int pos = row_ptr[d] + rank[e];
    float nrm = dinv[s] * dinv[d];
    long long v = ((long long)(unsigned)__float_as_int(nrm) << 32) | (unsigned)s;
    __builtin_nontemporal_store(v, csr + pos);
}

// ---------------- weight prep: W[K][M] fp32 -> Wt_hi/Wt_lo [M][K] f16 -------
__global__ void wprep_kernel(const float* __restrict__ W, f16* __restrict__ wt_hi,
                             f16* __restrict__ wt_lo, int K, int M) {
    int idx = blockIdx.x * 256 + threadIdx.x;
    if (idx >= K * M) return;
    int k = idx / M, m = idx % M;
    float w = W[idx];
    f16 h = (f16)w;
    wt_hi[(size_t)m * K + k] = h;
    wt_lo[(size_t)m * K + k] = (f16)(w - (float)h);
}

// ---------------- fp32 -> f16 convert (vectorized) ----------------
__global__ void f32to16_kernel(const float* __restrict__ x, f16* __restrict__ y, int n4) {
    int i = blockIdx.x * 256 + threadIdx.x;
    if (i < n4) {
        float4 v = ((const float4*)x)[i];
        union { f16 h[4]; uint2 u; } p;
        p.h[0] = (f16)v.x; p.h[1] = (f16)v.y; p.h[2] = (f16)v.z; p.h[3] = (f16)v.w;
        ((uint2*)y)[i] = p.u;
    }
}

// ---------------- f16 MFMA GEMM: out[N,M] = X[N,K] @ (Wh+Wl) (+bias,tanh) ---
// 256 thr = 4 waves. BM=128, BK=32. Each wave owns an SW=M/4 column strip and
// iterates all 8 row tiles. W pre-transposed [M][K], hi/lo split (f16 +
// remainder) so weight rounding is suppressed; fp32 accumulate.
template <int K, int M, bool BIAS_TANH, bool X_IS_HALF>
__global__ __launch_bounds__(256) void gemm_mfma_kernel(
    const void* __restrict__ Xv, const f16* __restrict__ Wth,
    const f16* __restrict__ Wtl, const float* __restrict__ bias,
    f16* __restrict__ out, int ld, int colOff, int N) {
    constexpr int BM = 128, BK = 32, XP = 40;
    constexpr int SW = M / 4;    // column strip per wave (32 or 16)
    constexpr int CT = SW / 16;  // 16-col tiles per wave (2 or 1)
    constexpr int RT = BM / 16;  // 8 row tiles
    __shared__ f16 xs[BM * XP];
    __shared__ f16 whs[M * XP];
    __shared__ f16 wls[M * XP];

    const int tid = threadIdx.x;
    const int lane = tid & 63;
    const int wv = tid >> 6;
    const int m16 = lane & 15;
    const int quad = lane >> 4;
    const int row0 = blockIdx.x * BM;

    f32x4 acc[RT][CT];
#pragma unroll
    for (int rt = 0; rt < RT; ++rt)
#pragma unroll
        for (int ct = 0; ct < CT; ++ct) acc[rt][ct] = (f32x4){0.f, 0.f, 0.f, 0.f};

    for (int k0 = 0; k0 < K; k0 += BK) {
        if (X_IS_HALF) {
            const f16* X = (const f16*)Xv;
#pragma unroll
            for (int i = 0; i < 2; ++i) {
                int c = i * 256 + tid;
                int r = c >> 2, ko = (c & 3) * 8;
                uint4 v = make_uint4(0u, 0u, 0u, 0u);
                if (row0 + r < N) v = *(const uint4*)(X + (size_t)(row0 + r) * K + k0 + ko);
                *(uint4*)(&xs[r * XP + ko]) = v;
            }
        } else {
            const float* X = (const float*)Xv;
#pragma unroll
            for (int i = 0; i < 4; ++i) {
                int c = i * 256 + tid;
                int r = c >> 3, kq = (c & 7) * 4;
                float4 v = make_float4(0.f, 0.f, 0.f, 0.f);
                if (row0 + r < N) v = *(const float4*)(X + (size_t)(row0 + r) * K + k0 + kq);
                union { f16 h[4]; uint2 u; } p;
                p.h[0] = (f16)v.x; p.h[1] = (f16)v.y; p.h[2] = (f16)v.z; p.h[3] = (f16)v.w;
                *(uint2*)(&xs[r * XP + kq]) = p.u;
            }
        }
#pragma unroll
        for (int i = 0; i < (M * 4) / 256; ++i) {
            int c = i * 256 + tid;
            int n = c >> 2, ko = (c & 3) * 8;
            *(uint4*)(&whs[n * XP + ko]) = *(const uint4*)(Wth + (size_t)n * K + k0 + ko);
            *(uint4*)(&wls[n * XP + ko]) = *(const uint4*)(Wtl + (size_t)n * K + k0 + ko);
        }
        __syncthreads();

        f16x8 bh[CT], bl[CT];
#pragma unroll
        for (int ct = 0; ct < CT; ++ct) {
            bh[ct] = *(const f16x8*)(&whs[(wv * SW + ct * 16 + m16) * XP + quad * 8]);
            bl[ct] = *(const f16x8*)(&wls[(wv * SW + ct * 16 + m16) * XP + quad * 8]);
        }
#pragma unroll
        for (int rt = 0; rt < RT; ++rt) {
            f16x8 a = *(const f16x8*)(&xs[(rt * 16 + m16) * XP + quad * 8]);
#pragma unroll
            for (int ct = 0; ct < CT; ++ct) {
                acc[rt][ct] = __builtin_amdgcn_mfma_f32_16x16x32_f16(a, bh[ct], acc[rt][ct], 0, 0, 0);
                acc[rt][ct] = __builtin_amdgcn_mfma_f32_16x16x32_f16(a, bl[ct], acc[rt][ct], 0, 0, 0);
            }
        }
        __syncthreads();
    }

    float brs[CT];
    if (BIAS_TANH) {
#pragma unroll
        for (int ct = 0; ct < CT; ++ct) brs[ct] = bias[wv * SW + ct * 16 + m16];
    }

    // C/D layout: col = lane&15, row(within 16) = quad*4 + reg
#pragma unroll
    for (int rt = 0; rt < RT; ++rt) {
#pragma unroll
        for (int r = 0; r < 4; ++r) {
            int row = row0 + rt * 16 + quad * 4 + r;
            if (row < N) {
                f16* op = out + (size_t)row * ld + colOff + wv * SW + m16;
#pragma unroll
                for (int ct = 0; ct < CT; ++ct) {
                    float v = acc[rt][ct][r];
                    if (BIAS_TANH) v = tanhf(v + brs[ct]);
                    op[ct * 16] = (f16)v;
                }
            }
        }
    }
}

// ---------------- f16 gather: out[i] = (tanh?)((b?) + xl[i]*dinv^2 + sum xl[j]*nrm)
// Output is a stream consumed sequentially by the next kernel -> NT stores,
// keeping L2 free for the random-access gather source.
template <int M, bool TANH, bool HAS_BIAS, bool OUT_F32>
__global__ __launch_bounds__(256) void gather_h_kernel(
    const f16* __restrict__ xl, const float* __restrict__ b,
    const float* __restrict__ dinv, const int* __restrict__ row_ptr,
    const int2* __restrict__ csr, void* __restrict__ outv,
    int ld, int colOff, int N) {
    constexpr int TPN = M / 8;  // threads per node (8 f16 = 16B each)
    int gid = blockIdx.x * 256 + threadIdx.x;
    int node = gid / TPN;
    int t = gid % TPN;
    if (node >= N) return;

    float di = dinv[node];
    float self = di * di;
    f16x8 x = *(const f16x8*)(xl + (size_t)node * M + t * 8);
    float acc[8];
#pragma unroll
    for (int j = 0; j < 8; ++j) acc[j] = (float)x[j] * self;
    if (HAS_BIAS) {
        float4 b0 = *(const float4*)(b + t * 8);
        float4 b1 = *(const float4*)(b + t * 8 + 4);
        acc[0] += b0.x; acc[1] += b0.y; acc[2] += b0.z; acc[3] += b0.w;
        acc[4] += b1.x; acc[5] += b1.y; acc[6] += b1.z; acc[7] += b1.w;
    }

    int p = row_ptr[node];
    const int p1 = row_ptr[node + 1];
    for (; p + 4 <= p1; p += 4) {  // 4 rows in flight
        int2 e0 = csr[p];
        int2 e1 = csr[p + 1];
        int2 e2 = csr[p + 2];
        int2 e3 = csr[p + 3];
        f16x8 v0 = *(const f16x8*)(xl + (size_t)e0.x * M + t * 8);
        f16x8 v1 = *(const f16x8*)(xl + (size_t)e1.x * M + t * 8);
        f16x8 v2 = *(const f16x8*)(xl + (size_t)e2.x * M + t * 8);
        f16x8 v3 = *(const f16x8*)(xl + (size_t)e3.x * M + t * 8);
        float n0 = __int_as_float(e0.y);
        float n1 = __int_as_float(e1.y);
        float n2 = __int_as_float(e2.y);
        float n3 = __int_as_float(e3.y);
#pragma unroll
        for (int j = 0; j < 8; ++j)
            acc[j] += ((float)v0[j] * n0 + (float)v1[j] * n1) +
                      ((float)v2[j] * n2 + (float)v3[j] * n3);
    }
    for (; p < p1; ++p) {
        int2 e0 = csr[p];
        f16x8 v0 = *(const f16x8*)(xl + (size_t)e0.x * M + t * 8);
        float n0 = __int_as_float(e0.y);
#pragma unroll
        for (int j = 0; j < 8; ++j) acc[j] += (float)v0[j] * n0;
    }

    if (TANH) {
#pragma unroll
        for (int j = 0; j < 8; ++j) acc[j] = tanhf(acc[j]);
    }

    if (OUT_F32) {
        float* op = (float*)outv + (size_t)node * ld + colOff + t * 8;
        f32x4 o0 = {acc[0], acc[1], acc[2], acc[3]};
        f32x4 o1 = {acc[4], acc[5], acc[6], acc[7]};
        __builtin_nontemporal_store(o0, (f32x4*)op);
        __builtin_nontemporal_store(o1, (f32x4*)(op + 4));
    } else {
        union { f16 h[8]; u32x4 u; } o;
#pragma unroll
        for (int j = 0; j < 8; ++j) o.h[j] = (f16)acc[j];
        __builtin_nontemporal_store(o.u, (u32x4*)((f16*)outv + (size_t)node * ld + colOff + t * 8));
    }
}

// ---------------------------------------------------------------------------
extern "C" void kernel_launch(void* const* d_in, const int* in_sizes, int n_in,
                              void* d_out, int out_size, void* d_ws, size_t ws_size,
                              hipStream_t stream) {
    const int FD = 256;

    const float* feature   = (const float*)d_in[0];
    const float* condition = (const float*)d_in[1];
    const int*   edge      = (const int*)d_in[2];
    const float* W_f2h = (const float*)d_in[3];
    const float* b_f2h = (const float*)d_in[4];
    const float* W_c2h = (const float*)d_in[5];
    const float* b_c2h = (const float*)d_in[6];
    const float* W_h2h = (const float*)d_in[7];
    const float* b_h2h = (const float*)d_in[8];
    const float* W_h2l = (const float*)d_in[9];
    const float* b_h2l = (const float*)d_in[10];
    float* out = (float*)d_out;

    const int N = in_sizes[0] / FD;   // 100000
    const int E = in_sizes[2] / 2;    // 1600000
    const int* src = edge;
    const int* dst = edge + E;

    // workspace layout
    float* ws_f   = (float*)d_ws;
    float* dinv   = ws_f;                                // N floats
    int*   count  = (int*)(ws_f + N);                    // N ints
    int*   rowp   = count + N;                           // N+1 ints
    int*   bsums  = rowp + N + 1;                        // 1024 ints
    int*   rank   = bsums + 1024;                        // E ints
    long long* csr = (long long*)(((uintptr_t)(rank + E) + 15) & ~(uintptr_t)15);  // E x 8B
    f16*   A_h    = (f16*)(csr + E);                     // N*128 f16 (xl scratch)
    f16*   B_h    = A_h + (size_t)N * 128;               // N*256 f16 (h; reused as H2)
    f16*   cond_h = B_h + (size_t)N * 256;               // N*64  f16
    f16*   wt1h   = cond_h + (size_t)N * 64;             // 128*256
    f16*   wt1l   = wt1h + 128 * 256;
    f16*   wt2h   = wt1l + 128 * 256;                    // 128*64
    f16*   wt2l   = wt2h + 128 * 64;
    f16*   wt3h   = wt2l + 128 * 64;                     // 128*256
    f16*   wt3l   = wt3h + 128 * 256;
    f16*   wt4h   = wt3l + 128 * 256;                    // 64*128
    f16*   wt4l   = wt4h + 64 * 128;

    const int TB = 256;
    dim3 blk(TB);
    const int nScanBlocks = (N + SCAN_TILE - 1) / SCAN_TILE;  // 49

    // --- weight prep + condition convert ---
    wprep_kernel<<<(256 * 128 + TB - 1) / TB, blk, 0, stream>>>(W_f2h, wt1h, wt1l, 256, 128);
    wprep_kernel<<<(64 * 128 + TB - 1) / TB, blk, 0, stream>>>(W_c2h, wt2h, wt2l, 64, 128);
    wprep_kernel<<<(256 * 128 + TB - 1) / TB, blk, 0, stream>>>(W_h2h, wt3h, wt3l, 256, 128);
    wprep_kernel<<<(128 * 64 + TB - 1) / TB, blk, 0, stream>>>(W_h2l, wt4h, wt4l, 128, 64);
    f32to16_kernel<<<(N * 16 + TB - 1) / TB, blk, 0, stream>>>(condition, cond_h, N * 16);

    // --- CSR build + norms (atomic-free fill via rank) ---
    count_zero_kernel<<<(N + TB - 1) / TB, blk, 0, stream>>>(count, N);
    count_rank_kernel<<<(E + TB - 1) / TB, blk, 0, stream>>>(dst, count, rank, E);
    dinv_kernel<<<(N + TB - 1) / TB, blk, 0, stream>>>(count, dinv, N);
    scan_partial_kernel<<<nScanBlocks, blk, 0, stream>>>(count, bsums, N);
    scan_blocksums_kernel<<<1, 1024, 0, stream>>>(bsums, nScanBlocks);
    scan_final_kernel<<<nScanBlocks, blk, 0, stream>>>(count, bsums, rowp, N);
    fill_kernel<<<(E + TB - 1) / TB, blk, 0, stream>>>(src, dst, rank, dinv, rowp, csr, E);

    const int gemm_grid = (N + 127) / 128;               // 782
    const int g128 = (N * 16 + TB - 1) / TB;             // gather grid, M=128 (TPN=16)
    const int g64  = (N * 8 + TB - 1) / TB;              // gather grid, M=64  (TPN=8)

    // --- conv1: f2h = tanh(P(feature@W)+b) -> B_h[:, 0:128] ---
    gemm_mfma_kernel<256, 128, false, false><<<gemm_grid, blk, 0, stream>>>(
        feature, wt1h, wt1l, nullptr, A_h, 128, 0, N);
    gather_h_kernel<128, true, true, false><<<g128, blk, 0, stream>>>(
        A_h, b_f2h, dinv, rowp, (const int2*)csr, B_h, 256, 0, N);

    // --- conv2 (reordered): cprop = P*condition (f16, 64-wide), then tanh(cprop@W+b) ---
    gather_h_kernel<64, false, false, false><<<g64, blk, 0, stream>>>(
        cond_h, nullptr, dinv, rowp, (const int2*)csr, A_h, 64, 0, N);
    gemm_mfma_kernel<64, 128, true, true><<<gemm_grid, blk, 0, stream>>>(
        A_h, wt2h, wt2l, b_c2h, B_h, 256, 128, N);

    // --- conv3: h2 = tanh(P (h @ W_h2h) + b); H2 reuses B_h compact N x 128 ---
    gemm_mfma_kernel<256, 128, false, true><<<gemm_grid, blk, 0, stream>>>(
        B_h, wt3h, wt3l, nullptr, A_h, 128, 0, N);
    gather_h_kernel<128, true, true, false><<<g128, blk, 0, stream>>>(
        A_h, b_h2h, dinv, rowp, (const int2*)csr, B_h, 128, 0, N);

    // --- conv4: z = P (h2 @ W_h2l) + b -> fp32 out ---
    gemm_mfma_kernel<128, 64, false, true><<<gemm_grid, blk, 0, stream>>>(
        B_h, wt4h, wt4l, nullptr, A_h, 64, 0, N);
    gather_h_kernel<64, false, true, true><<<g64, blk, 0, stream>>>(
        A_h, b_h2l, dinv, rowp, (const int2*)csr, out, 64, 0, N);
}